// Round 18
// baseline (2282.198 us; speedup 1.0000x reference)
//
#include <hip/hip_runtime.h>
#include <cstdint>
#include <math.h>

typedef unsigned short ushort_t;
typedef __bf16 bf16x8 __attribute__((ext_vector_type(8)));
typedef float f32x4 __attribute__((ext_vector_type(4)));

#define BNSCALE 0.9999950000374998f

__device__ __forceinline__ ushort_t f2b(float x){
  union { float f; uint32_t u; } v; v.f = x;
  uint32_t u = v.u;
  u = u + 0x7fffu + ((u >> 16) & 1u);
  return (ushort_t)(u >> 16);
}
__device__ __forceinline__ float b2f(ushort_t h){
  union { float f; uint32_t u; } v; v.u = ((uint32_t)h) << 16; return v.f;
}

__device__ __forceinline__ uint32_t rotl32(uint32_t x, int d){ return (x<<d)|(x>>(32-d)); }

__device__ __forceinline__ void threefry2x32(uint32_t& x0, uint32_t& x1){
  const uint32_t ks0=0u, ks1=42u, ks2=42u^0x1BD11BDAu;
  x0+=ks0; x1+=ks1;
  x0+=x1; x1=rotl32(x1,13); x1^=x0;
  x0+=x1; x1=rotl32(x1,15); x1^=x0;
  x0+=x1; x1=rotl32(x1,26); x1^=x0;
  x0+=x1; x1=rotl32(x1, 6); x1^=x0;
  x0+=ks1; x1+=ks2+1u;
  x0+=x1; x1=rotl32(x1,17); x1^=x0;
  x0+=x1; x1=rotl32(x1,29); x1^=x0;
  x0+=x1; x1=rotl32(x1,16); x1^=x0;
  x0+=x1; x1=rotl32(x1,24); x1^=x0;
  x0+=ks2; x1+=ks0+2u;
  x0+=x1; x1=rotl32(x1,13); x1^=x0;
  x0+=x1; x1=rotl32(x1,15); x1^=x0;
  x0+=x1; x1=rotl32(x1,26); x1^=x0;
  x0+=x1; x1=rotl32(x1, 6); x1^=x0;
  x0+=ks0; x1+=ks1+3u;
  x0+=x1; x1=rotl32(x1,17); x1^=x0;
  x0+=x1; x1=rotl32(x1,29); x1^=x0;
  x0+=x1; x1=rotl32(x1,16); x1^=x0;
  x0+=x1; x1=rotl32(x1,24); x1^=x0;
  x0+=ks1; x1+=ks2+4u;
  x0+=x1; x1=rotl32(x1,13); x1^=x0;
  x0+=x1; x1=rotl32(x1,15); x1^=x0;
  x0+=x1; x1=rotl32(x1,26); x1^=x0;
  x0+=x1; x1=rotl32(x1, 6); x1^=x0;
  x0+=ks2; x1+=ks0+5u;
}

// ---------------- start conv (t-major: x[b][t][o][n]) ----------------
__global__ void k_start(const float* __restrict__ hist, const float* __restrict__ sw,
                        const float* __restrict__ sb, float* __restrict__ x){
  int idx = blockIdx.x*256 + threadIdx.x;
  int n = idx & 511; int r = idx >> 9;
  int o = r & 31; int r2 = r >> 5;
  int t = r2 % 13; int b = r2 / 13;
  float acc = sb[o];
  if (t > 0){
    const float* h = hist + ((size_t)(b*12 + (t-1))*512 + n)*3;
    acc += h[0]*sw[o*2+0] + h[1]*sw[o*2+1];
  }
  x[(((size_t)(b*13 + t)*32 + o))*512 + n] = acc;
}

// ---------------- nodevec graph ----------------
__global__ void k_gw_mm(const float* __restrict__ nv1, const float* __restrict__ nv2,
                        float* __restrict__ gw){
  int idx = blockIdx.x*256+threadIdx.x;
  int w = idx & 511, v = idx >> 9;
  float acc=0.f;
  #pragma unroll
  for (int k=0;k<64;k++) acc += nv1[v*64+k]*nv2[k*512+w];
  gw[idx]=acc;
}

// softmax + fused split-bf16 write (replaces separate k_split on gwb)
__global__ void k_gw_sm(float* __restrict__ gw, ushort_t* __restrict__ hi,
                        ushort_t* __restrict__ lo){
  int v = blockIdx.x; int tid=threadIdx.x;
  float a0 = fmaxf(gw[v*512+tid],0.f), a1=fmaxf(gw[v*512+256+tid],0.f);
  __shared__ float red[256];
  red[tid]=fmaxf(a0,a1); __syncthreads();
  for(int s=128;s>0;s>>=1){ if(tid<s) red[tid]=fmaxf(red[tid],red[tid+s]); __syncthreads(); }
  float m = red[0]; __syncthreads();
  float e0=expf(a0-m), e1=expf(a1-m);
  red[tid]=e0+e1; __syncthreads();
  for(int s=128;s>0;s>>=1){ if(tid<s) red[tid]+=red[tid+s]; __syncthreads(); }
  float inv = 1.0f/red[0];
  float v0 = e0*inv, v1 = e1*inv;
  gw[v*512+tid]=v0; gw[v*512+256+tid]=v1;
  ushort_t h0 = f2b(v0);
  hi[v*512+tid] = h0; lo[v*512+tid] = f2b(v0 - b2f(h0));
  ushort_t h1 = f2b(v1);
  hi[v*512+256+tid] = h1; lo[v*512+256+tid] = f2b(v1 - b2f(h1));
}

// ---------------- embedding (exact 12-pt DFT twiddles) ----------------
__global__ void k_embed(const float* __restrict__ hist, const float* __restrict__ Ex1,
                        const float* __restrict__ node1, const float* __restrict__ TiD,
                        const float* __restrict__ DiW, float* __restrict__ e){
  const float c12[12] = {1.f, 0.8660254037844387f, 0.5f, 0.f, -0.5f, -0.8660254037844387f,
                         -1.f, -0.8660254037844387f, -0.5f, 0.f, 0.5f, 0.8660254037844387f};
  const float s12[12] = {0.f, -0.5f, -0.8660254037844387f, -1.f, -0.8660254037844387f, -0.5f,
                         0.f, 0.5f, 0.8660254037844387f, 1.f, 0.8660254037844387f, 0.5f};
  int row = blockIdx.x; int b = row >> 9; int n = row & 511;
  int tid = threadIdx.x;
  __shared__ float fr[7];
  if (tid < 7){
    float re=0.f, im=0.f;
    for (int l=0;l<12;l++){
      float v = hist[((size_t)(b*12+l)*512+n)*3];
      int idx = (tid*l) % 12;
      re += v*c12[idx]; im += v*s12[idx];
    }
    fr[tid]=sqrtf(re*re+im*im);
  }
  __syncthreads();
  float* er = e + (size_t)row*152;
  float acc=0.f;
  #pragma unroll
  for (int f=0;f<7;f++) acc += fr[f]*Ex1[f*64+tid];
  er[tid]=acc;
  er[64+tid]=node1[n*64+tid];
  if (tid<12){
    int it = (int)(hist[((size_t)(b*12+11)*512+n)*3+1]*288.0f);
    int id = (int)(hist[((size_t)(b*12+11)*512+n)*3+2]*7.0f);
    er[128+tid]=TiD[it*12+tid];
    er[140+tid]=DiW[id*12+tid];
  }
}

// ---------------- adp = e @ Wd[n] (Wd read once) ----------------
__global__ void k_adp(const float* __restrict__ e, const float* __restrict__ Wd,
                      float* __restrict__ adp){
  int n = blockIdx.x; int tid = threadIdx.x; // 128 threads
  __shared__ float es[16][152];
  for (int idx = tid; idx < 16*152; idx += 128){
    int r = idx / 152, q = idx - r*152;
    es[r][q] = e[((size_t)(r*512+n))*152 + q];
  }
  __syncthreads();
  const float* w = Wd + (size_t)n*152*128;
  float acc[16];
  #pragma unroll
  for (int r=0;r<16;r++) acc[r]=0.f;
  for (int q = 0; q < 152; q++){
    float wv = w[q*128 + tid];
    #pragma unroll
    for (int r = 0; r < 16; r++) acc[r] += es[r][q]*wv;
  }
  #pragma unroll
  for (int r=0;r<16;r++) adp[((size_t)(r*512+n))*128 + tid] = acc[r];
}

// ---------------- layernorm stats, two-stage ----------------
__global__ void k_lnp1(const float* __restrict__ adp, float* __restrict__ part){
  int blk = blockIdx.x; int tid = threadIdx.x;
  const float* p = adp + (size_t)(blk>>4)*65536 + (size_t)(blk&15)*4096;
  float s=0.f, s2=0.f;
  for (int i=tid;i<4096;i+=256){ float v=p[i]; s+=v; s2+=v*v; }
  __shared__ float rs[256], rs2[256];
  rs[tid]=s; rs2[tid]=s2; __syncthreads();
  for(int k=128;k>0;k>>=1){ if(tid<k){rs[tid]+=rs[tid+k]; rs2[tid]+=rs2[tid+k];} __syncthreads(); }
  if(tid==0){ part[blk*2]=rs[0]; part[blk*2+1]=rs2[0]; }
}

__global__ void k_lnp2(const float* __restrict__ part, float* __restrict__ stats){
  int tid = threadIdx.x; // 256
  int b = tid >> 4, c = tid & 15;
  float s = part[tid*2], s2 = part[tid*2+1];
  #pragma unroll
  for (int off=8; off>=1; off>>=1){ s += __shfl_down(s,off); s2 += __shfl_down(s2,off); }
  if (c==0){
    float mu = s/65536.f; float var = s2/65536.f - mu*mu;
    stats[b*2]=mu; stats[b*2+1]=rsqrtf(var+1e-8f);
  }
}

// ---------------- t = norm(adp) @ Wxabs ----------------
__global__ void k_xw(const float* __restrict__ adp, const float* __restrict__ Wx,
                     const float* __restrict__ stats, float* __restrict__ t){
  int row=blockIdx.x; int tid=threadIdx.x; int b=row>>9;
  __shared__ float as[128];
  as[tid]=(adp[(size_t)row*128+tid]-stats[2*b])*stats[2*b+1];
  __syncthreads();
  float acc=0.f;
  #pragma unroll 8
  for(int k=0;k<128;k++) acc += as[k]*Wx[k*128+tid];
  t[(size_t)row*128+tid]=acc;
}

// ---------------- adj = relu(t @ norm(adp)^T) ----------------
__global__ __launch_bounds__(256) void k_adjmm(const float* __restrict__ T,
                        const float* __restrict__ P, const float* __restrict__ stats,
                        float* __restrict__ adj){
  int b = blockIdx.z;
  int n0 = blockIdx.y*32, m0 = blockIdx.x*64;
  const float* Tb = T + (size_t)b*512*128;
  const float* Pb = P + (size_t)b*512*128;
  float mu = stats[2*b], isig = stats[2*b+1];
  __shared__ float Ts[32][33];
  __shared__ float Ps[64][33];
  int tid=threadIdx.x; int tx=tid&15, ty=tid>>4;
  float acc[2][4]={};
  for(int k0=0;k0<128;k0+=32){
    for(int q=0;q<4;q++){ int idx=tid+q*256; int r=idx>>5, kk=idx&31; Ts[r][kk]=Tb[(size_t)(n0+r)*128+k0+kk]; }
    for(int q=0;q<8;q++){ int idx=tid+q*256; int r=idx>>5, kk=idx&31; Ps[r][kk]=(Pb[(size_t)(m0+r)*128+k0+kk]-mu)*isig; }
    __syncthreads();
    #pragma unroll
    for(int kk=0;kk<32;kk++){
      float t0=Ts[ty][kk], t1=Ts[ty+16][kk];
      float p0=Ps[tx*4+0][kk], p1=Ps[tx*4+1][kk], p2=Ps[tx*4+2][kk], p3=Ps[tx*4+3][kk];
      acc[0][0]+=t0*p0; acc[0][1]+=t0*p1; acc[0][2]+=t0*p2; acc[0][3]+=t0*p3;
      acc[1][0]+=t1*p0; acc[1][1]+=t1*p1; acc[1][2]+=t1*p2; acc[1][3]+=t1*p3;
    }
    __syncthreads();
  }
  for(int i2=0;i2<2;i2++){
    int n=n0+ty+16*i2;
    float4 o4=make_float4(fmaxf(acc[i2][0],0.f),fmaxf(acc[i2][1],0.f),
                          fmaxf(acc[i2][2],0.f),fmaxf(acc[i2][3],0.f));
    *(float4*)&adj[((size_t)b*512+n)*512+m0+tx*4]=o4;
  }
}

// ---------------- top-20 + mask + softmax*0.5, fused split-bf16 write ----------------
__global__ void k_topk(float* __restrict__ adj, ushort_t* __restrict__ adjh,
                       ushort_t* __restrict__ adjl){
  const int row = blockIdx.x;
  const int tid = threadIdx.x;
  const uint32_t halfn = 2097152u;
  float a[8], v[8];
  const bool lowhalf = row < 4096;
  #pragma unroll
  for(int k=0;k<8;k++){
    int m = k*64+tid;
    uint32_t i = (uint32_t)row*512u + (uint32_t)m;
    uint32_t c0 = lowhalf ? i : i - halfn;
    uint32_t x0=c0, x1=c0+halfn;
    threefry2x32(x0,x1);
    uint32_t bits = lowhalf ? x0 : x1;
    float u = __uint_as_float((bits>>9)|0x3f800000u)-1.0f;
    a[k]=adj[(size_t)row*512+m];
    v[k]=a[k]+0.01f*u;
  }
  unsigned selmask=0u;
  for(int it=0; it<20; it++){
    float best=-1e30f; int bi=0x7fffffff;
    #pragma unroll
    for(int k=0;k<8;k++){
      if(!((selmask>>k)&1u)){
        int m=k*64+tid;
        if(v[k]>best || (v[k]==best && m<bi)){best=v[k]; bi=m;}
      }
    }
    #pragma unroll
    for(int off=32; off>=1; off>>=1){
      float ov=__shfl_xor(best,off); int oi=__shfl_xor(bi,off);
      if(ov>best || (ov==best && oi<bi)){best=ov; bi=oi;}
    }
    if((bi&63)==tid) selmask |= 1u<<(bi>>6);
  }
  float M=0.f;
  #pragma unroll
  for(int k=0;k<8;k++) if((selmask>>k)&1u) M=fmaxf(M,a[k]);
  #pragma unroll
  for(int off=32;off>=1;off>>=1) M=fmaxf(M,__shfl_xor(M,off));
  float S=0.f;
  #pragma unroll
  for(int k=0;k<8;k++) S += expf((((selmask>>k)&1u)? a[k]:0.f) - M);
  #pragma unroll
  for(int off=32;off>=1;off>>=1) S += __shfl_xor(S,off);
  float inv = 0.5f/S;
  #pragma unroll
  for(int k=0;k<8;k++){
    int m=k*64+tid;
    float val = expf((((selmask>>k)&1u)? a[k]:0.f)-M)*inv;
    size_t o = (size_t)row*512+m;
    adj[o] = val;
    ushort_t h = f2b(val);
    adjh[o] = h;
    adjl[o] = f2b(val - b2f(h));
  }
}

// ---------------- fp32 -> split bf16 with transpose (per batch) ----------------
__global__ void k_splitT(const float* __restrict__ src, long sBS,
                         ushort_t* __restrict__ hi, long hBS, int hRS,
                         ushort_t* __restrict__ lo, long lBS, int lRS){
  int b = blockIdx.z;
  int c0 = blockIdx.x*32, r0 = blockIdx.y*32;
  __shared__ float tile[32][33];
  int tx = threadIdx.x & 31, ty = threadIdx.x >> 5;
  for (int q = 0; q < 4; q++)
    tile[ty+q*8][tx] = src[b*sBS + (size_t)(r0+ty+q*8)*512 + c0+tx];
  __syncthreads();
  for (int q = 0; q < 4; q++){
    int cc = c0+ty+q*8, rr = r0+tx;
    float v = tile[tx][ty+q*8];
    ushort_t h = f2b(v);
    hi[b*hBS + (size_t)cc*hRS + rr] = h;
    lo[b*lBS + (size_t)cc*lRS + rr] = f2b(v - b2f(h));
  }
}

// ---------------- k_pow: 64x64-tile split-bf16 power GEMM, split write ----------------
__global__ __launch_bounds__(256,2) void k_pow(
    const ushort_t* __restrict__ Ah, const ushort_t* __restrict__ Al, long aBS,
    const ushort_t* __restrict__ Bh, const ushort_t* __restrict__ Bl, long bBS,
    ushort_t* __restrict__ Ch, ushort_t* __restrict__ Cl, long cBS){
  __shared__ __align__(16) ushort_t At[5120];  // hi [64][40], lo at +2560
  __shared__ __align__(16) ushort_t Bt[5120];
  const int b = blockIdx.z;
  const int r0 = blockIdx.x*64, n0 = blockIdx.y*64;
  const int tid = threadIdx.x;
  const int w = tid >> 6, l = tid & 63, lr = l & 15, kg = l >> 4;
  const int wr = w & 1, wc = w >> 1;
  const int ra = tid >> 2, ca = (tid & 3)*8;
  const ushort_t* Ahp = Ah + (long)b*aBS + (long)(r0+ra)*512 + ca;
  const ushort_t* Alp = Al + (long)b*aBS + (long)(r0+ra)*512 + ca;
  const ushort_t* Bhp = Bh + (long)b*bBS + (long)(n0+ra)*512 + ca;
  const ushort_t* Blp = Bl + (long)b*bBS + (long)(n0+ra)*512 + ca;
  f32x4 acc[2][2];
  #pragma unroll
  for (int ms=0; ms<2; ms++)
    #pragma unroll
    for (int ns=0; ns<2; ns++) acc[ms][ns] = (f32x4){0.f,0.f,0.f,0.f};
  uint4 pA0,pA1,pB0,pB1;
  #define LDP(K0) { \
    pA0 = *(const uint4*)(Ahp + (K0)); pA1 = *(const uint4*)(Alp + (K0)); \
    pB0 = *(const uint4*)(Bhp + (K0)); pB1 = *(const uint4*)(Blp + (K0)); }
  LDP(0);
  for (int k0 = 0; k0 < 512; k0 += 32){
    __syncthreads();
    *(uint4*)&At[ra*40 + ca]        = pA0;
    *(uint4*)&At[2560 + ra*40 + ca] = pA1;
    *(uint4*)&Bt[ra*40 + ca]        = pB0;
    *(uint4*)&Bt[2560 + ra*40 + ca] = pB1;
    __syncthreads();
    if (k0 + 32 < 512) LDP(k0 + 32);
    bf16x8 ahv[2], alv[2], bhv[2], blv[2];
    #pragma unroll
    for (int ms=0; ms<2; ms++){
      int ar = wr*32 + ms*16 + lr;
      ahv[ms] = *(const bf16x8*)&At[ar*40 + kg*8];
      alv[ms] = *(const bf16x8*)&At[2560 + ar*40 + kg*8];
    }
    #pragma unroll
    for (int ns=0; ns<2; ns++){
      int br = wc*32 + ns*16 + lr;
      bhv[ns] = *(const bf16x8*)&Bt[br*40 + kg*8];
      blv[ns] = *(const bf16x8*)&Bt[2560 + br*40 + kg*8];
    }
    #pragma unroll
    for (int ms=0; ms<2; ms++)
      #pragma unroll
      for (int ns=0; ns<2; ns++){
        acc[ms][ns] = __builtin_amdgcn_mfma_f32_16x16x32_bf16(ahv[ms], bhv[ns], acc[ms][ns], 0, 0, 0);
        acc[ms][ns] = __builtin_amdgcn_mfma_f32_16x16x32_bf16(alv[ms], bhv[ns], acc[ms][ns], 0, 0, 0);
        acc[ms][ns] = __builtin_amdgcn_mfma_f32_16x16x32_bf16(ahv[ms], blv[ns], acc[ms][ns], 0, 0, 0);
      }
  }
  #undef LDP
  #pragma unroll
  for (int ms=0; ms<2; ms++)
    #pragma unroll
    for (int rg=0; rg<4; rg++){
      int r = r0 + wr*32 + ms*16 + kg*4 + rg;
      #pragma unroll
      for (int ns=0; ns<2; ns++){
        int n = n0 + wc*32 + ns*16 + lr;
        float v = acc[ms][ns][rg];
        long ofs = (long)b*cBS + (long)r*512 + n;
        ushort_t hv = f2b(v);
        Ch[ofs] = hv;
        Cl[ofs] = f2b(v - b2f(hv));
      }
    }
}

// ---------------- layer GEMM: 64x64 tile, 4 zones INSIDE K-loop (round-14 proven) ----------------
__global__ __launch_bounds__(256,1) void k_gemms(
    const ushort_t* __restrict__ Afh, const ushort_t* __restrict__ Afl,
    const ushort_t* __restrict__ S0h, const ushort_t* __restrict__ S0l,
    const ushort_t* __restrict__ S1h, const ushort_t* __restrict__ S1l,
    const ushort_t* __restrict__ S2h, const ushort_t* __restrict__ S2l,
    const ushort_t* __restrict__ S3h, const ushort_t* __restrict__ S3l,
    const float* __restrict__ gcw, float* __restrict__ xnew,
    int Mt, int M, int lo){
  __shared__ __align__(16) char smem[51200];
  ushort_t* At = (ushort_t*)smem;              // hi [64][40] (5120B), lo at +2560 ush
  ushort_t* Bt = (ushort_t*)(smem + 10240);    // zone z at +z*5120 ush {hi, lo at +2560}
  float* m32 = (float*)smem;                   // epilogue: [64][66] f32 (16896B)
  float* Wgs = (float*)(smem + 16896);         // epilogue: [4][32 c2][32 c] (16384B)
  // XCD-chunked swizzle
  const int total = gridDim.x;
  const int chunk = total >> 3;
  const int lid = blockIdx.x;
  const int swz = (lid & 7)*chunk + (lid >> 3);
  const int x = swz % Mt;
  const int rest = swz / Mt;
  const int y = rest & 7;
  const int b = rest >> 3;
  const int n0 = y*64, r0 = x*64;
  const int tid = threadIdx.x;
  const int w = tid >> 6, l = tid & 63, lr = l & 15, kg = l >> 4;
  const int wr = w & 1, wc = w >> 1;
  // A staging: row ra = tid>>2, 8-ushort chunk ca
  const int ra = tid >> 2, ca = (tid & 3)*8;
  int arow = r0 + ra; if (arow >= M) arow = M - 1;
  const ushort_t* Ahp = Afh + (long)b*M*512 + (long)arow*512 + ca;
  const ushort_t* Alp = Afl + (long)b*M*512 + (long)arow*512 + ca;
  // B staging: zone zz = tid>>6, row rb = tid&63 (full 32-ushort row, hi+lo)
  const int zz = tid >> 6, rb = tid & 63;
  const ushort_t* Bz; const ushort_t* Bzl;
  if (zz == 0){ Bz = S0h; Bzl = S0l; }
  else if (zz == 1){ Bz = S1h; Bzl = S1l; }
  else if (zz == 2){ Bz = S2h + (long)b*262144; Bzl = S2l + (long)b*262144; }
  else { Bz = S3h + (long)b*262144; Bzl = S3l + (long)b*262144; }
  const ushort_t* Bhp = Bz + (long)(n0 + rb)*512;
  const ushort_t* Blp = Bzl + (long)(n0 + rb)*512;

  f32x4 acc[4][2][2];
  #pragma unroll
  for (int z=0; z<4; z++)
    #pragma unroll
    for (int ms=0; ms<2; ms++)
      #pragma unroll
      for (int ns=0; ns<2; ns++) acc[z][ms][ns] = (f32x4){0.f,0.f,0.f,0.f};

  uint4 pA0,pA1,pB0,pB1,pB2,pB3,pB4,pB5,pB6,pB7;
  #define LDG(K0) { \
    pA0 = *(const uint4*)(Ahp + (K0)); pA1 = *(const uint4*)(Alp + (K0)); \
    pB0 = *(const uint4*)(Bhp + (K0));      pB1 = *(const uint4*)(Bhp + (K0) + 8); \
    pB2 = *(const uint4*)(Bhp + (K0) + 16); pB3 = *(const uint4*)(Bhp + (K0) + 24); \
    pB4 = *(const uint4*)(Blp + (K0));      pB5 = *(const uint4*)(Blp + (K0) + 8); \
    pB6 = *(const uint4*)(Blp + (K0) + 16); pB7 = *(const uint4*)(Blp + (K0) + 24); }
  LDG(0);
  for (int k0 = 0; k0 < 512; k0 += 32){
    __syncthreads();
    *(uint4*)&At[ra*40 + ca]        = pA0;
    *(uint4*)&At[2560 + ra*40 + ca] = pA1;
    {
      ushort_t* bb = Bt + zz*5120 + rb*40;
      *(uint4*)&bb[0]  = pB0; *(uint4*)&bb[8]  = pB1;
      *(uint4*)&bb[16] = pB2; *(uint4*)&bb[24] = pB3;
      ushort_t* bl2 = bb + 2560;
      *(uint4*)&bl2[0]  = pB4; *(uint4*)&bl2[8]  = pB5;
      *(uint4*)&bl2[16] = pB6; *(uint4*)&bl2[24] = pB7;
    }
    __syncthreads();
    if (k0 + 32 < 512) LDG(k0 + 32);
    bf16x8 ahv[2], alv[2];
    #pragma unroll
    for (int ms=0; ms<2; ms++){
      int ar = wr*32 + ms*16 + lr;
      ahv[ms] = *(const bf16x8*)&At[ar*40 + kg*8];
      alv[ms] = *(const bf16x8*)&At[2560 + ar*40 + kg*8];
    }
    #pragma unroll
    for (int z=0; z<4; z++){
      #pragma unroll
      for (int ns=0; ns<2; ns++){
        int br = wc*32 + ns*16 + lr;
        bf16x8 bh = *(const bf16x8*)&Bt[z*5120 + br*40 + kg*8];
        bf16x8 bl = *(const bf16x8*)&Bt[z*5120 + 2560 + br*40 + kg*8];
        #pragma unroll
        for (int ms=0; ms<2; ms++){
          acc[z][ms][ns] = __builtin_amdgcn_mfma_f32_16x16x32_bf16(ahv[ms], bh, acc[z][ms][ns], 0, 0, 0);
          acc[z][ms][ns] = __builtin_amdgcn_mfma_f32_16x16x32_bf16(alv[ms], bh, acc[z][ms][ns], 0, 0, 0);
          acc[z][ms][ns] = __builtin_amdgcn_mfma_f32_16x16x32_bf16(ahv[ms], bl, acc[z][ms][ns], 0, 0, 0);
        }
      }
    }
  }
  #undef LDG
  // ---- epilogue: Wgs(T) load, then per-zone LDS round-trip + channel mix ----
  __syncthreads();
  for (int idx = tid; idx < 4096; idx += 256){
    int z = idx >> 10, rem = idx & 1023;
    int c2 = rem >> 5, c = rem & 31;
    Wgs[idx] = gcw[c*160 + (z+1)*32 + c2];     // transposed: [z][c2][c]
  }
  const int g = tid >> 6, j = tid & 63;   // active threads: tid<128 -> (g in {0,1}, j)
  float outv[32];
  #pragma unroll
  for (int c=0; c<32; c++) outv[c] = 0.f;
  #pragma unroll
  for (int z=0; z<4; z++){
    __syncthreads();
    #pragma unroll
    for (int ms=0; ms<2; ms++)
      #pragma unroll
      for (int ns=0; ns<2; ns++)
        #pragma unroll
        for (int rg=0; rg<4; rg++)
          m32[(wr*32 + ms*16 + kg*4 + rg)*66 + wc*32 + ns*16 + lr] = acc[z][ms][ns][rg];
    __syncthreads();
    if (tid < 128){
      const float* wzT = Wgs + z*1024;
      for (int c2=0; c2<32; c2++){
        float yv = m32[(g*32 + c2)*66 + j];
        const float* wrow = wzT + c2*32;
        #pragma unroll
        for (int c=0; c<32; c++) outv[c] += wrow[c]*yv;
      }
    }
  }
  if (tid < 128 && r0 + g*32 < M){
    int t = (r0 >> 5) + g;
    long ob = ((long)(b*lo + t)*32)*512 + n0 + j;
    #pragma unroll
    for (int c=0; c<32; c++){
      long ofs = ob + (long)c*512;
      xnew[ofs] += outv[c]*BNSCALE;
    }
  }
}

// ---------------- mix1: tconv+act -> fg(split), base*BNSCALE -> xnew,
// ---------------- FUSED skip accumulation at t==lo-1 (replaces k_skipacc) ----------------
__global__ void k_mix1(const float* __restrict__ x,
    const float* __restrict__ fw, const float* __restrict__ fb,
    const float* __restrict__ gwv, const float* __restrict__ gb,
    const float* __restrict__ gcw, const float* __restrict__ gcb,
    const float* __restrict__ sw, const float* __restrict__ sb,
    float* __restrict__ skip, int init,
    ushort_t* __restrict__ fgh, ushort_t* __restrict__ fgl,
    float* __restrict__ xnew,
    int d, int li, int lo){
  __shared__ float FWs[2048], GWs[2048], W0s[1024];
  __shared__ float fbs[32], gbs[32], gcbs[32];
  int tid = threadIdx.x;
  int t = blockIdx.y, b = blockIdx.z;
  int n = blockIdx.x*256 + tid;
  for (int idx = tid; idx < 2048; idx += 256){ FWs[idx] = fw[idx]; GWs[idx] = gwv[idx]; }
  for (int idx = tid; idx < 1024; idx += 256) W0s[idx] = gcw[(idx>>5)*160 + (idx&31)];
  if (tid < 32){ fbs[tid]=fb[tid]; gbs[tid]=gb[tid]; gcbs[tid]=gcb[tid]; }
  __syncthreads();
  float xv[32], xv2[32], fgv[32];
  const float* xb  = x + ((size_t)(b*li + t)*32)*512 + n;
  const float* xb2 = x + ((size_t)(b*li + t + d)*32)*512 + n;
  #pragma unroll
  for (int c=0;c<32;c++){ xv[c] = xb[(size_t)c*512]; xv2[c] = xb2[(size_t)c*512]; }
  #pragma unroll
  for (int o=0;o<32;o++){
    float f = fbs[o], g = gbs[o];
    #pragma unroll
    for (int c=0;c<32;c++){
      float2 wf = *(const float2*)&FWs[(o*32+c)*2];
      float2 wg = *(const float2*)&GWs[(o*32+c)*2];
      f += xv[c]*wf.x + xv2[c]*wf.y;
      g += xv[c]*wg.x + xv2[c]*wg.y;
    }
    f = fminf(f, 15.f);
    float e2 = __expf(2.f*f);
    float th = (e2 - 1.f)/(e2 + 1.f);
    float sg = 1.f/(1.f + __expf(-g));
    fgv[o] = th*sg;
  }
  size_t rbase = ((size_t)(b*lo + t)*32)*512 + n;
  #pragma unroll
  for (int o=0;o<32;o++){
    float bs = gcbs[o] + xv2[o];
    #pragma unroll
    for (int c=0;c<32;c++) bs += W0s[o*32+c]*fgv[c];
    xnew[rbase + (size_t)o*512] = bs*BNSCALE;
    ushort_t h = f2b(fgv[o]);
    fgh[rbase + (size_t)o*512] = h;
    fgl[rbase + (size_t)o*512] = f2b(fgv[o] - b2f(h));
  }
  if (t == lo-1){
    // fused skip accumulation: thread owns node n, holds all 32 fg channels.
    // sw/sb reads are thread-uniform -> scalar loads.
    for (int s = 0; s < 256; s++){
      float acc = sb[s];
      #pragma unroll
      for (int c = 0; c < 32; c++) acc += sw[s*32+c]*fgv[c];
      size_t o = ((size_t)b*256+s)*512 + n;
      skip[o] = init ? acc : skip[o] + acc;
    }
  }
}

// ---------------- end1: tiled GEMM with relu in/out ----------------
__global__ __launch_bounds__(256) void k_end1t(const float* __restrict__ skip,
                        const float* __restrict__ w, const float* __restrict__ bias,
                        float* __restrict__ h){
  int b = blockIdx.z; int e0 = blockIdx.y*32; int n0 = blockIdx.x*64;
  __shared__ float Ws_[32][33];
  __shared__ float Ss_[32][64];
  int tid = threadIdx.x, tx = tid&15, ty = tid>>4;
  float acc[2][4] = {};
  for (int k0 = 0; k0 < 256; k0 += 32){
    for (int q2 = 0; q2 < 4; q2++){ int idx = tid + q2*256; int r = idx>>5, kk = idx&31;
      Ws_[r][kk] = w[(size_t)(e0+r)*256 + k0+kk]; }
    for (int q2 = 0; q2 < 8; q2++){ int idx = tid + q2*256; int r = idx>>6, ww = idx&63;
      Ss_[r][ww] = fmaxf(skip[(size_t)b*131072 + (size_t)(k0+r)*512 + n0+ww], 0.f); }
    __syncthreads();
    #pragma unroll
    for (int kk = 0; kk < 32; kk++){
      float t0 = Ws_[ty][kk], t1 = Ws_[ty+16][kk];
      float4 b4 = *(float4*)&Ss_[kk][tx*4];
      acc[0][0]+=t0*b4.x; acc[0][1]+=t0*b4.y; acc[0][2]+=t0*b4.z; acc[0][3]+=t0*b4.w;
      acc[1][0]+=t1*b4.x; acc[1][1]+=t1*b4.y; acc[1][2]+=t1*b4.z; acc[1][3]+=t1*b4.w;
    }
    __syncthreads();
  }
  for (int i2 = 0; i2 < 2; i2++){
    int e = e0 + ty + 16*i2;
    float bb = bias[e];
    float4 o4 = make_float4(fmaxf(acc[i2][0]+bb,0.f), fmaxf(acc[i2][1]+bb,0.f),
                            fmaxf(acc[i2][2]+bb,0.f), fmaxf(acc[i2][3]+bb,0.f));
    *(float4*)&h[(size_t)b*262144 + (size_t)e*512 + n0 + tx*4] = o4;
  }
}

__global__ void k_end2(const float* __restrict__ h, const float* __restrict__ w,
                       const float* __restrict__ bias, float* __restrict__ out){
  int n = blockIdx.x*256+threadIdx.x; int o=blockIdx.y; int b=blockIdx.z;
  float acc=bias[o];
  const float* hb=h + (size_t)b*262144 + n;
  #pragma unroll 8
  for (int e=0;e<512;e++) acc += w[o*512+e]*hb[(size_t)e*512];
  out[((size_t)b*12+o)*512+n]=acc;
}

extern "C" void kernel_launch(void* const* d_in, const int* in_sizes, int n_in,
                              void* d_out, int out_size, void* d_ws, size_t ws_size,
                              hipStream_t stream) {
  (void)in_sizes; (void)n_in; (void)out_size;
  const float* hist   =(const float*)d_in[0];
  const float* start_w=(const float*)d_in[1];
  const float* start_b=(const float*)d_in[2];
  const float* filt_w =(const float*)d_in[3];
  const float* filt_b =(const float*)d_in[4];
  const float* gate_w =(const float*)d_in[5];
  const float* gate_b =(const float*)d_in[6];
  const float* skip_w =(const float*)d_in[7];
  const float* skip_b =(const float*)d_in[8];
  const float* gconv_w=(const float*)d_in[9];
  const float* gconv_b=(const float*)d_in[10];
  const float* end1_w =(const float*)d_in[11];
  const float* end1_b =(const float*)d_in[12];
  const float* end2_w =(const float*)d_in[13];
  const float* end2_b =(const float*)d_in[14];
  const float* Ex1    =(const float*)d_in[15];
  const float* node1  =(const float*)d_in[16];
  const float* Wd     =(const float*)d_in[17];
  const float* Wxabs  =(const float*)d_in[18];
  const float* TiD    =(const float*)d_in[19];
  const float* DiW    =(const float*)d_in[20];
  const float* nv1    =(const float*)d_in[21];
  const float* nv2    =(const float*)d_in[22];

  char* ws = (char*)d_ws;
  const size_t needed = 83902464;
  if (ws_size < needed) return;

  // ---- persistent layout (bytes) ----
  ushort_t* PtA_hi  = (ushort_t*)(ws + 0);         //   524,288  A^T [m][512]
  ushort_t* PtA_lo  = (ushort_t*)(ws + 524288);
  ushort_t* PtA2_hi = (ushort_t*)(ws + 1048576);   //   524,288  (A^2)^T
  ushort_t* PtA2_lo = (ushort_t*)(ws + 1572864);
  ushort_t* PtB_hi  = (ushort_t*)(ws + 2097152);   // 8,388,608  B^T [b][m][512]
  ushort_t* PtB_lo  = (ushort_t*)(ws + 10485760);
  ushort_t* PtB2_hi = (ushort_t*)(ws + 18874368);  // 8,388,608  (B^2)^T
  ushort_t* PtB2_lo = (ushort_t*)(ws + 27262976);
  float*    stats   = (float*)(ws + 35651584);     // 128
  float*    part    = (float*)(ws + 35651712);     // 2,048 (pad to 16K)
  float*    skip    = (float*)(ws + 35667968);     // 8,388,608
  float*    fgL     = (float*)(ws + 44056576);     // 1,048,576 (unused, kept for layout)
  ushort_t* fgh     = (ushort_t*)(ws + 45105152);  // 6,291,456  [b][t][c][512]
  ushort_t* fgl     = (ushort_t*)(ws + 51396608);  // 6,291,456
  float*    xA      = (float*)(ws + 57688064);     // 13,631,488 [b][t][c][512] li=13
  float*    xB      = (float*)(ws + 71319552);     // 12,582,912 lo<=12
  (void)fgL;
  // ---- prologue aliases (region [44,056,576 .. 83,902,464) dead during prologue) ----
  float*    gwb     = (float*)(ws + 44056576);     // 1,048,576
  ushort_t* gws_hi  = (ushort_t*)(ws + 45105152);  //   524,288 (A non-T split)
  ushort_t* gws_lo  = (ushort_t*)(ws + 45629440);
  float*    ebuf    = (float*)(ws + 46153728);     // 4,980,736 (dead after k_adp)
  ushort_t* adjh    = (ushort_t*)(ws + 46153728);  // 4,194,304 (over ex-ebuf)
  float*    adp     = (float*)(ws + 51134464);     // 4,194,304
  float*    xw      = (float*)(ws + 55328768);     // 4,194,304
  float*    adjb    = (float*)(ws + 59523072);     // 16,777,216
  ushort_t* adjl    = (ushort_t*)(ws + 76300288);  // 4,194,304
  // ---- epilogue alias (fg/x dead after layer loop) ----
  float*    hbuf    = (float*)(ws + 45105152);     // 16,777,216

  // ======== prologue: adjacency supports ========
  k_embed<<<dim3(8192),dim3(64),0,stream>>>(hist,Ex1,node1,TiD,DiW,ebuf);
  k_adp<<<dim3(512),dim3(128),0,stream>>>(ebuf,Wd,adp);          // ebuf dead after this
  k_gw_mm<<<dim3(1024),dim3(256),0,stream>>>(nv1,nv2,gwb);
  k_gw_sm<<<dim3(512),dim3(256),0,stream>>>(gwb, gws_hi, gws_lo);
  k_splitT<<<dim3(16,16,1),dim3(256),0,stream>>>(gwb, 0, PtA_hi, 0, 512, PtA_lo, 0, 512);
  // A^2 power: (A^T)^2 -> PtA2 (split-write)
  k_pow<<<dim3(8,8,1),dim3(256),0,stream>>>(
      PtA_hi, PtA_lo, 0, gws_hi, gws_lo, 0, PtA2_hi, PtA2_lo, 0);
  k_lnp1<<<dim3(256),dim3(256),0,stream>>>(adp,part);
  k_lnp2<<<dim3(1),dim3(256),0,stream>>>(part,stats);
  k_xw<<<dim3(8192),dim3(128),0,stream>>>(adp,Wxabs,stats,xw);
  k_adjmm<<<dim3(8,16,16),dim3(256),0,stream>>>(xw,adp,stats,adjb);
  k_topk<<<dim3(8192),dim3(64),0,stream>>>(adjb, adjh, adjl);
  k_splitT<<<dim3(16,16,16),dim3(256),0,stream>>>(adjb, 262144, PtB_hi, 262144, 512,
                                                  PtB_lo, 262144, 512);
  // B^2 power per batch: (B^T)^2 -> PtB2 (split-write)
  k_pow<<<dim3(8,8,16),dim3(256),0,stream>>>(
      PtB_hi, PtB_lo, 262144, adjh, adjl, 262144, PtB2_hi, PtB2_lo, 262144);

  k_start<<<dim3(13312),dim3(256),0,stream>>>(hist,start_w,start_b,xA);

  // ======== layer loop ========
  const int lin[8]={13,12,10,9,7,6,4,3};
  const int dil[8]={1,2,1,2,1,2,1,2};
  float* xcur=xA; float* alt=xB;
  for (int i=0;i<8;i++){
    int d=dil[i], li=lin[i], lo=li-d;
    const float* fwp=filt_w+(size_t)i*2048; const float* fbp=filt_b+i*32;
    const float* gwp=gate_w+(size_t)i*2048; const float* gbp=gate_b+i*32;
    const float* swp=skip_w+(size_t)i*8192; const float* sbp=skip_b+i*256;
    const float* gcwp=gconv_w+(size_t)i*5120; const float* gcbp=gconv_b+i*32;
    int M = 32*lo, Mt = (M+63)/64;

    k_mix1<<<dim3(2,lo,16),dim3(256),0,stream>>>(xcur,fwp,fbp,gwp,gbp,gcwp,gcbp,
        swp,sbp,skip,(i==0)?1:0,
        fgh,fgl,alt,d,li,lo);

    if (i < 7){
      k_gemms<<<dim3(Mt*8*16),dim3(256),0,stream>>>(
          fgh, fgl,
          PtA_hi, PtA_lo, PtA2_hi, PtA2_lo, PtB_hi, PtB_lo, PtB2_hi, PtB2_lo,
          gcwp, alt, Mt, M, lo);
    }
    float* tmp=xcur; xcur=alt; alt=tmp;
  }

  // ======== head ========
  k_end1t<<<dim3(8,16,16),dim3(256),0,stream>>>(skip,end1_w,end1_b,hbuf);
  k_end2<<<dim3(2,12,16),dim3(256),0,stream>>>(hbuf,end2_w,end2_b,(float*)d_out);
}

// Round 19
// 1216.670 us; speedup vs baseline: 1.8758x; 1.8758x over previous
//
#include <hip/hip_runtime.h>
#include <cstdint>
#include <math.h>

typedef unsigned short ushort_t;
typedef __bf16 bf16x8 __attribute__((ext_vector_type(8)));
typedef float f32x4 __attribute__((ext_vector_type(4)));

#define BNSCALE 0.9999950000374998f

__device__ __forceinline__ ushort_t f2b(float x){
  union { float f; uint32_t u; } v; v.f = x;
  uint32_t u = v.u;
  u = u + 0x7fffu + ((u >> 16) & 1u);
  return (ushort_t)(u >> 16);
}
__device__ __forceinline__ float b2f(ushort_t h){
  union { float f; uint32_t u; } v; v.u = ((uint32_t)h) << 16; return v.f;
}

__device__ __forceinline__ uint32_t rotl32(uint32_t x, int d){ return (x<<d)|(x>>(32-d)); }

__device__ __forceinline__ void threefry2x32(uint32_t& x0, uint32_t& x1){
  const uint32_t ks0=0u, ks1=42u, ks2=42u^0x1BD11BDAu;
  x0+=ks0; x1+=ks1;
  x0+=x1; x1=rotl32(x1,13); x1^=x0;
  x0+=x1; x1=rotl32(x1,15); x1^=x0;
  x0+=x1; x1=rotl32(x1,26); x1^=x0;
  x0+=x1; x1=rotl32(x1, 6); x1^=x0;
  x0+=ks1; x1+=ks2+1u;
  x0+=x1; x1=rotl32(x1,17); x1^=x0;
  x0+=x1; x1=rotl32(x1,29); x1^=x0;
  x0+=x1; x1=rotl32(x1,16); x1^=x0;
  x0+=x1; x1=rotl32(x1,24); x1^=x0;
  x0+=ks2; x1+=ks0+2u;
  x0+=x1; x1=rotl32(x1,13); x1^=x0;
  x0+=x1; x1=rotl32(x1,15); x1^=x0;
  x0+=x1; x1=rotl32(x1,26); x1^=x0;
  x0+=x1; x1=rotl32(x1, 6); x1^=x0;
  x0+=ks0; x1+=ks1+3u;
  x0+=x1; x1=rotl32(x1,17); x1^=x0;
  x0+=x1; x1=rotl32(x1,29); x1^=x0;
  x0+=x1; x1=rotl32(x1,16); x1^=x0;
  x0+=x1; x1=rotl32(x1,24); x1^=x0;
  x0+=ks1; x1+=ks2+4u;
  x0+=x1; x1=rotl32(x1,13); x1^=x0;
  x0+=x1; x1=rotl32(x1,15); x1^=x0;
  x0+=x1; x1=rotl32(x1,26); x1^=x0;
  x0+=x1; x1=rotl32(x1, 6); x1^=x0;
  x0+=ks2; x1+=ks0+5u;
}

// ---------------- start conv (t-major: x[b][t][o][n]) ----------------
__global__ void k_start(const float* __restrict__ hist, const float* __restrict__ sw,
                        const float* __restrict__ sb, float* __restrict__ x){
  int idx = blockIdx.x*256 + threadIdx.x;
  int n = idx & 511; int r = idx >> 9;
  int o = r & 31; int r2 = r >> 5;
  int t = r2 % 13; int b = r2 / 13;
  float acc = sb[o];
  if (t > 0){
    const float* h = hist + ((size_t)(b*12 + (t-1))*512 + n)*3;
    acc += h[0]*sw[o*2+0] + h[1]*sw[o*2+1];
  }
  x[(((size_t)(b*13 + t)*32 + o))*512 + n] = acc;
}

// ---------------- nodevec graph ----------------
__global__ void k_gw_mm(const float* __restrict__ nv1, const float* __restrict__ nv2,
                        float* __restrict__ gw){
  int idx = blockIdx.x*256+threadIdx.x;
  int w = idx & 511, v = idx >> 9;
  float acc=0.f;
  #pragma unroll
  for (int k=0;k<64;k++) acc += nv1[v*64+k]*nv2[k*512+w];
  gw[idx]=acc;
}

// softmax + fused split-bf16 write
__global__ void k_gw_sm(float* __restrict__ gw, ushort_t* __restrict__ hi,
                        ushort_t* __restrict__ lo){
  int v = blockIdx.x; int tid=threadIdx.x;
  float a0 = fmaxf(gw[v*512+tid],0.f), a1=fmaxf(gw[v*512+256+tid],0.f);
  __shared__ float red[256];
  red[tid]=fmaxf(a0,a1); __syncthreads();
  for(int s=128;s>0;s>>=1){ if(tid<s) red[tid]=fmaxf(red[tid],red[tid+s]); __syncthreads(); }
  float m = red[0]; __syncthreads();
  float e0=expf(a0-m), e1=expf(a1-m);
  red[tid]=e0+e1; __syncthreads();
  for(int s=128;s>0;s>>=1){ if(tid<s) red[tid]+=red[tid+s]; __syncthreads(); }
  float inv = 1.0f/red[0];
  float v0 = e0*inv, v1 = e1*inv;
  gw[v*512+tid]=v0; gw[v*512+256+tid]=v1;
  ushort_t h0 = f2b(v0);
  hi[v*512+tid] = h0; lo[v*512+tid] = f2b(v0 - b2f(h0));
  ushort_t h1 = f2b(v1);
  hi[v*512+256+tid] = h1; lo[v*512+256+tid] = f2b(v1 - b2f(h1));
}

// ---------------- embedding (exact 12-pt DFT twiddles) ----------------
__global__ void k_embed(const float* __restrict__ hist, const float* __restrict__ Ex1,
                        const float* __restrict__ node1, const float* __restrict__ TiD,
                        const float* __restrict__ DiW, float* __restrict__ e){
  const float c12[12] = {1.f, 0.8660254037844387f, 0.5f, 0.f, -0.5f, -0.8660254037844387f,
                         -1.f, -0.8660254037844387f, -0.5f, 0.f, 0.5f, 0.8660254037844387f};
  const float s12[12] = {0.f, -0.5f, -0.8660254037844387f, -1.f, -0.8660254037844387f, -0.5f,
                         0.f, 0.5f, 0.8660254037844387f, 1.f, 0.8660254037844387f, 0.5f};
  int row = blockIdx.x; int b = row >> 9; int n = row & 511;
  int tid = threadIdx.x;
  __shared__ float fr[7];
  if (tid < 7){
    float re=0.f, im=0.f;
    for (int l=0;l<12;l++){
      float v = hist[((size_t)(b*12+l)*512+n)*3];
      int idx = (tid*l) % 12;
      re += v*c12[idx]; im += v*s12[idx];
    }
    fr[tid]=sqrtf(re*re+im*im);
  }
  __syncthreads();
  float* er = e + (size_t)row*152;
  float acc=0.f;
  #pragma unroll
  for (int f=0;f<7;f++) acc += fr[f]*Ex1[f*64+tid];
  er[tid]=acc;
  er[64+tid]=node1[n*64+tid];
  if (tid<12){
    int it = (int)(hist[((size_t)(b*12+11)*512+n)*3+1]*288.0f);
    int id = (int)(hist[((size_t)(b*12+11)*512+n)*3+2]*7.0f);
    er[128+tid]=TiD[it*12+tid];
    er[140+tid]=DiW[id*12+tid];
  }
}

// ---------------- adp = e @ Wd[n] (Wd read once) ----------------
__global__ void k_adp(const float* __restrict__ e, const float* __restrict__ Wd,
                      float* __restrict__ adp){
  int n = blockIdx.x; int tid = threadIdx.x; // 128 threads
  __shared__ float es[16][152];
  for (int idx = tid; idx < 16*152; idx += 128){
    int r = idx / 152, q = idx - r*152;
    es[r][q] = e[((size_t)(r*512+n))*152 + q];
  }
  __syncthreads();
  const float* w = Wd + (size_t)n*152*128;
  float acc[16];
  #pragma unroll
  for (int r=0;r<16;r++) acc[r]=0.f;
  for (int q = 0; q < 152; q++){
    float wv = w[q*128 + tid];
    #pragma unroll
    for (int r = 0; r < 16; r++) acc[r] += es[r][q]*wv;
  }
  #pragma unroll
  for (int r=0;r<16;r++) adp[((size_t)(r*512+n))*128 + tid] = acc[r];
}

// ---------------- layernorm stats, two-stage ----------------
__global__ void k_lnp1(const float* __restrict__ adp, float* __restrict__ part){
  int blk = blockIdx.x; int tid = threadIdx.x;
  const float* p = adp + (size_t)(blk>>4)*65536 + (size_t)(blk&15)*4096;
  float s=0.f, s2=0.f;
  for (int i=tid;i<4096;i+=256){ float v=p[i]; s+=v; s2+=v*v; }
  __shared__ float rs[256], rs2[256];
  rs[tid]=s; rs2[tid]=s2; __syncthreads();
  for(int k=128;k>0;k>>=1){ if(tid<k){rs[tid]+=rs[tid+k]; rs2[tid]+=rs2[tid+k];} __syncthreads(); }
  if(tid==0){ part[blk*2]=rs[0]; part[blk*2+1]=rs2[0]; }
}

__global__ void k_lnp2(const float* __restrict__ part, float* __restrict__ stats){
  int tid = threadIdx.x; // 256
  int b = tid >> 4, c = tid & 15;
  float s = part[tid*2], s2 = part[tid*2+1];
  #pragma unroll
  for (int off=8; off>=1; off>>=1){ s += __shfl_down(s,off); s2 += __shfl_down(s2,off); }
  if (c==0){
    float mu = s/65536.f; float var = s2/65536.f - mu*mu;
    stats[b*2]=mu; stats[b*2+1]=rsqrtf(var+1e-8f);
  }
}

// ---------------- t = norm(adp) @ Wxabs ----------------
__global__ void k_xw(const float* __restrict__ adp, const float* __restrict__ Wx,
                     const float* __restrict__ stats, float* __restrict__ t){
  int row=blockIdx.x; int tid=threadIdx.x; int b=row>>9;
  __shared__ float as[128];
  as[tid]=(adp[(size_t)row*128+tid]-stats[2*b])*stats[2*b+1];
  __syncthreads();
  float acc=0.f;
  #pragma unroll 8
  for(int k=0;k<128;k++) acc += as[k]*Wx[k*128+tid];
  t[(size_t)row*128+tid]=acc;
}

// ---------------- adj = relu(t @ norm(adp)^T) ----------------
__global__ __launch_bounds__(256) void k_adjmm(const float* __restrict__ T,
                        const float* __restrict__ P, const float* __restrict__ stats,
                        float* __restrict__ adj){
  int b = blockIdx.z;
  int n0 = blockIdx.y*32, m0 = blockIdx.x*64;
  const float* Tb = T + (size_t)b*512*128;
  const float* Pb = P + (size_t)b*512*128;
  float mu = stats[2*b], isig = stats[2*b+1];
  __shared__ float Ts[32][33];
  __shared__ float Ps[64][33];
  int tid=threadIdx.x; int tx=tid&15, ty=tid>>4;
  float acc[2][4]={};
  for(int k0=0;k0<128;k0+=32){
    for(int q=0;q<4;q++){ int idx=tid+q*256; int r=idx>>5, kk=idx&31; Ts[r][kk]=Tb[(size_t)(n0+r)*128+k0+kk]; }
    for(int q=0;q<8;q++){ int idx=tid+q*256; int r=idx>>5, kk=idx&31; Ps[r][kk]=(Pb[(size_t)(m0+r)*128+k0+kk]-mu)*isig; }
    __syncthreads();
    #pragma unroll
    for(int kk=0;kk<32;kk++){
      float t0=Ts[ty][kk], t1=Ts[ty+16][kk];
      float p0=Ps[tx*4+0][kk], p1=Ps[tx*4+1][kk], p2=Ps[tx*4+2][kk], p3=Ps[tx*4+3][kk];
      acc[0][0]+=t0*p0; acc[0][1]+=t0*p1; acc[0][2]+=t0*p2; acc[0][3]+=t0*p3;
      acc[1][0]+=t1*p0; acc[1][1]+=t1*p1; acc[1][2]+=t1*p2; acc[1][3]+=t1*p3;
    }
    __syncthreads();
  }
  for(int i2=0;i2<2;i2++){
    int n=n0+ty+16*i2;
    float4 o4=make_float4(fmaxf(acc[i2][0],0.f),fmaxf(acc[i2][1],0.f),
                          fmaxf(acc[i2][2],0.f),fmaxf(acc[i2][3],0.f));
    *(float4*)&adj[((size_t)b*512+n)*512+m0+tx*4]=o4;
  }
}

// ---------------- top-20 + mask + softmax*0.5, fused split-bf16 write ----------------
__global__ void k_topk(float* __restrict__ adj, ushort_t* __restrict__ adjh,
                       ushort_t* __restrict__ adjl){
  const int row = blockIdx.x;
  const int tid = threadIdx.x;
  const uint32_t halfn = 2097152u;
  float a[8], v[8];
  const bool lowhalf = row < 4096;
  #pragma unroll
  for(int k=0;k<8;k++){
    int m = k*64+tid;
    uint32_t i = (uint32_t)row*512u + (uint32_t)m;
    uint32_t c0 = lowhalf ? i : i - halfn;
    uint32_t x0=c0, x1=c0+halfn;
    threefry2x32(x0,x1);
    uint32_t bits = lowhalf ? x0 : x1;
    float u = __uint_as_float((bits>>9)|0x3f800000u)-1.0f;
    a[k]=adj[(size_t)row*512+m];
    v[k]=a[k]+0.01f*u;
  }
  unsigned selmask=0u;
  for(int it=0; it<20; it++){
    float best=-1e30f; int bi=0x7fffffff;
    #pragma unroll
    for(int k=0;k<8;k++){
      if(!((selmask>>k)&1u)){
        int m=k*64+tid;
        if(v[k]>best || (v[k]==best && m<bi)){best=v[k]; bi=m;}
      }
    }
    #pragma unroll
    for(int off=32; off>=1; off>>=1){
      float ov=__shfl_xor(best,off); int oi=__shfl_xor(bi,off);
      if(ov>best || (ov==best && oi<bi)){best=ov; bi=oi;}
    }
    if((bi&63)==tid) selmask |= 1u<<(bi>>6);
  }
  float M=0.f;
  #pragma unroll
  for(int k=0;k<8;k++) if((selmask>>k)&1u) M=fmaxf(M,a[k]);
  #pragma unroll
  for(int off=32;off>=1;off>>=1) M=fmaxf(M,__shfl_xor(M,off));
  float S=0.f;
  #pragma unroll
  for(int k=0;k<8;k++) S += expf((((selmask>>k)&1u)? a[k]:0.f) - M);
  #pragma unroll
  for(int off=32;off>=1;off>>=1) S += __shfl_xor(S,off);
  float inv = 0.5f/S;
  #pragma unroll
  for(int k=0;k<8;k++){
    int m=k*64+tid;
    float val = expf((((selmask>>k)&1u)? a[k]:0.f)-M)*inv;
    size_t o = (size_t)row*512+m;
    adj[o] = val;
    ushort_t h = f2b(val);
    adjh[o] = h;
    adjl[o] = f2b(val - b2f(h));
  }
}

// ---------------- fp32 -> split bf16 with transpose (per batch) ----------------
__global__ void k_splitT(const float* __restrict__ src, long sBS,
                         ushort_t* __restrict__ hi, long hBS, int hRS,
                         ushort_t* __restrict__ lo, long lBS, int lRS){
  int b = blockIdx.z;
  int c0 = blockIdx.x*32, r0 = blockIdx.y*32;
  __shared__ float tile[32][33];
  int tx = threadIdx.x & 31, ty = threadIdx.x >> 5;
  for (int q = 0; q < 4; q++)
    tile[ty+q*8][tx] = src[b*sBS + (size_t)(r0+ty+q*8)*512 + c0+tx];
  __syncthreads();
  for (int q = 0; q < 4; q++){
    int cc = c0+ty+q*8, rr = r0+tx;
    float v = tile[tx][ty+q*8];
    ushort_t h = f2b(v);
    hi[b*hBS + (size_t)cc*hRS + rr] = h;
    lo[b*lBS + (size_t)cc*lRS + rr] = f2b(v - b2f(h));
  }
}

// ---------------- k_pow: 64x64-tile split-bf16 power GEMM, split write ----------------
__global__ __launch_bounds__(256,2) void k_pow(
    const ushort_t* __restrict__ Ah, const ushort_t* __restrict__ Al, long aBS,
    const ushort_t* __restrict__ Bh, const ushort_t* __restrict__ Bl, long bBS,
    ushort_t* __restrict__ Ch, ushort_t* __restrict__ Cl, long cBS){
  __shared__ __align__(16) ushort_t At[5120];  // hi [64][40], lo at +2560
  __shared__ __align__(16) ushort_t Bt[5120];
  const int b = blockIdx.z;
  const int r0 = blockIdx.x*64, n0 = blockIdx.y*64;
  const int tid = threadIdx.x;
  const int w = tid >> 6, l = tid & 63, lr = l & 15, kg = l >> 4;
  const int wr = w & 1, wc = w >> 1;
  const int ra = tid >> 2, ca = (tid & 3)*8;
  const ushort_t* Ahp = Ah + (long)b*aBS + (long)(r0+ra)*512 + ca;
  const ushort_t* Alp = Al + (long)b*aBS + (long)(r0+ra)*512 + ca;
  const ushort_t* Bhp = Bh + (long)b*bBS + (long)(n0+ra)*512 + ca;
  const ushort_t* Blp = Bl + (long)b*bBS + (long)(n0+ra)*512 + ca;
  f32x4 acc[2][2];
  #pragma unroll
  for (int ms=0; ms<2; ms++)
    #pragma unroll
    for (int ns=0; ns<2; ns++) acc[ms][ns] = (f32x4){0.f,0.f,0.f,0.f};
  uint4 pA0,pA1,pB0,pB1;
  #define LDP(K0) { \
    pA0 = *(const uint4*)(Ahp + (K0)); pA1 = *(const uint4*)(Alp + (K0)); \
    pB0 = *(const uint4*)(Bhp + (K0)); pB1 = *(const uint4*)(Blp + (K0)); }
  LDP(0);
  for (int k0 = 0; k0 < 512; k0 += 32){
    __syncthreads();
    *(uint4*)&At[ra*40 + ca]        = pA0;
    *(uint4*)&At[2560 + ra*40 + ca] = pA1;
    *(uint4*)&Bt[ra*40 + ca]        = pB0;
    *(uint4*)&Bt[2560 + ra*40 + ca] = pB1;
    __syncthreads();
    if (k0 + 32 < 512) LDP(k0 + 32);
    bf16x8 ahv[2], alv[2], bhv[2], blv[2];
    #pragma unroll
    for (int ms=0; ms<2; ms++){
      int ar = wr*32 + ms*16 + lr;
      ahv[ms] = *(const bf16x8*)&At[ar*40 + kg*8];
      alv[ms] = *(const bf16x8*)&At[2560 + ar*40 + kg*8];
    }
    #pragma unroll
    for (int ns=0; ns<2; ns++){
      int br = wc*32 + ns*16 + lr;
      bhv[ns] = *(const bf16x8*)&Bt[br*40 + kg*8];
      blv[ns] = *(const bf16x8*)&Bt[2560 + br*40 + kg*8];
    }
    #pragma unroll
    for (int ms=0; ms<2; ms++)
      #pragma unroll
      for (int ns=0; ns<2; ns++){
        acc[ms][ns] = __builtin_amdgcn_mfma_f32_16x16x32_bf16(ahv[ms], bhv[ns], acc[ms][ns], 0, 0, 0);
        acc[ms][ns] = __builtin_amdgcn_mfma_f32_16x16x32_bf16(alv[ms], bhv[ns], acc[ms][ns], 0, 0, 0);
        acc[ms][ns] = __builtin_amdgcn_mfma_f32_16x16x32_bf16(ahv[ms], blv[ns], acc[ms][ns], 0, 0, 0);
      }
  }
  #undef LDP
  #pragma unroll
  for (int ms=0; ms<2; ms++)
    #pragma unroll
    for (int rg=0; rg<4; rg++){
      int r = r0 + wr*32 + ms*16 + kg*4 + rg;
      #pragma unroll
      for (int ns=0; ns<2; ns++){
        int n = n0 + wc*32 + ns*16 + lr;
        float v = acc[ms][ns][rg];
        long ofs = (long)b*cBS + (long)r*512 + n;
        ushort_t hv = f2b(v);
        Ch[ofs] = hv;
        Cl[ofs] = f2b(v - b2f(hv));
      }
    }
}

// ---------------- layer GEMM: 64x64 tile, 4 zones INSIDE K-loop (round-14 proven) ----------------
__global__ __launch_bounds__(256,1) void k_gemms(
    const ushort_t* __restrict__ Afh, const ushort_t* __restrict__ Afl,
    const ushort_t* __restrict__ S0h, const ushort_t* __restrict__ S0l,
    const ushort_t* __restrict__ S1h, const ushort_t* __restrict__ S1l,
    const ushort_t* __restrict__ S2h, const ushort_t* __restrict__ S2l,
    const ushort_t* __restrict__ S3h, const ushort_t* __restrict__ S3l,
    const float* __restrict__ gcw, float* __restrict__ xnew,
    int Mt, int M, int lo){
  __shared__ __align__(16) char smem[51200];
  ushort_t* At = (ushort_t*)smem;              // hi [64][40] (5120B), lo at +2560 ush
  ushort_t* Bt = (ushort_t*)(smem + 10240);    // zone z at +z*5120 ush {hi, lo at +2560}
  float* m32 = (float*)smem;                   // epilogue: [64][66] f32 (16896B)
  float* Wgs = (float*)(smem + 16896);         // epilogue: [4][32 c2][32 c] (16384B)
  // XCD-chunked swizzle
  const int total = gridDim.x;
  const int chunk = total >> 3;
  const int lid = blockIdx.x;
  const int swz = (lid & 7)*chunk + (lid >> 3);
  const int x = swz % Mt;
  const int rest = swz / Mt;
  const int y = rest & 7;
  const int b = rest >> 3;
  const int n0 = y*64, r0 = x*64;
  const int tid = threadIdx.x;
  const int w = tid >> 6, l = tid & 63, lr = l & 15, kg = l >> 4;
  const int wr = w & 1, wc = w >> 1;
  // A staging: row ra = tid>>2, 8-ushort chunk ca
  const int ra = tid >> 2, ca = (tid & 3)*8;
  int arow = r0 + ra; if (arow >= M) arow = M - 1;
  const ushort_t* Ahp = Afh + (long)b*M*512 + (long)arow*512 + ca;
  const ushort_t* Alp = Afl + (long)b*M*512 + (long)arow*512 + ca;
  // B staging: zone zz = tid>>6, row rb = tid&63 (full 32-ushort row, hi+lo)
  const int zz = tid >> 6, rb = tid & 63;
  const ushort_t* Bz; const ushort_t* Bzl;
  if (zz == 0){ Bz = S0h; Bzl = S0l; }
  else if (zz == 1){ Bz = S1h; Bzl = S1l; }
  else if (zz == 2){ Bz = S2h + (long)b*262144; Bzl = S2l + (long)b*262144; }
  else { Bz = S3h + (long)b*262144; Bzl = S3l + (long)b*262144; }
  const ushort_t* Bhp = Bz + (long)(n0 + rb)*512;
  const ushort_t* Blp = Bzl + (long)(n0 + rb)*512;

  f32x4 acc[4][2][2];
  #pragma unroll
  for (int z=0; z<4; z++)
    #pragma unroll
    for (int ms=0; ms<2; ms++)
      #pragma unroll
      for (int ns=0; ns<2; ns++) acc[z][ms][ns] = (f32x4){0.f,0.f,0.f,0.f};

  uint4 pA0,pA1,pB0,pB1,pB2,pB3,pB4,pB5,pB6,pB7;
  #define LDG(K0) { \
    pA0 = *(const uint4*)(Ahp + (K0)); pA1 = *(const uint4*)(Alp + (K0)); \
    pB0 = *(const uint4*)(Bhp + (K0));      pB1 = *(const uint4*)(Bhp + (K0) + 8); \
    pB2 = *(const uint4*)(Bhp + (K0) + 16); pB3 = *(const uint4*)(Bhp + (K0) + 24); \
    pB4 = *(const uint4*)(Blp + (K0));      pB5 = *(const uint4*)(Blp + (K0) + 8); \
    pB6 = *(const uint4*)(Blp + (K0) + 16); pB7 = *(const uint4*)(Blp + (K0) + 24); }
  LDG(0);
  for (int k0 = 0; k0 < 512; k0 += 32){
    __syncthreads();
    *(uint4*)&At[ra*40 + ca]        = pA0;
    *(uint4*)&At[2560 + ra*40 + ca] = pA1;
    {
      ushort_t* bb = Bt + zz*5120 + rb*40;
      *(uint4*)&bb[0]  = pB0; *(uint4*)&bb[8]  = pB1;
      *(uint4*)&bb[16] = pB2; *(uint4*)&bb[24] = pB3;
      ushort_t* bl2 = bb + 2560;
      *(uint4*)&bl2[0]  = pB4; *(uint4*)&bl2[8]  = pB5;
      *(uint4*)&bl2[16] = pB6; *(uint4*)&bl2[24] = pB7;
    }
    __syncthreads();
    if (k0 + 32 < 512) LDG(k0 + 32);
    bf16x8 ahv[2], alv[2];
    #pragma unroll
    for (int ms=0; ms<2; ms++){
      int ar = wr*32 + ms*16 + lr;
      ahv[ms] = *(const bf16x8*)&At[ar*40 + kg*8];
      alv[ms] = *(const bf16x8*)&At[2560 + ar*40 + kg*8];
    }
    #pragma unroll
    for (int z=0; z<4; z++){
      #pragma unroll
      for (int ns=0; ns<2; ns++){
        int br = wc*32 + ns*16 + lr;
        bf16x8 bh = *(const bf16x8*)&Bt[z*5120 + br*40 + kg*8];
        bf16x8 bl = *(const bf16x8*)&Bt[z*5120 + 2560 + br*40 + kg*8];
        #pragma unroll
        for (int ms=0; ms<2; ms++){
          acc[z][ms][ns] = __builtin_amdgcn_mfma_f32_16x16x32_bf16(ahv[ms], bh, acc[z][ms][ns], 0, 0, 0);
          acc[z][ms][ns] = __builtin_amdgcn_mfma_f32_16x16x32_bf16(alv[ms], bh, acc[z][ms][ns], 0, 0, 0);
          acc[z][ms][ns] = __builtin_amdgcn_mfma_f32_16x16x32_bf16(ahv[ms], bl, acc[z][ms][ns], 0, 0, 0);
        }
      }
    }
  }
  #undef LDG
  // ---- epilogue: Wgs(T) load, then per-zone LDS round-trip + channel mix ----
  __syncthreads();
  for (int idx = tid; idx < 4096; idx += 256){
    int z = idx >> 10, rem = idx & 1023;
    int c2 = rem >> 5, c = rem & 31;
    Wgs[idx] = gcw[c*160 + (z+1)*32 + c2];     // transposed: [z][c2][c]
  }
  const int g = tid >> 6, j = tid & 63;   // active threads: tid<128 -> (g in {0,1}, j)
  float outv[32];
  #pragma unroll
  for (int c=0; c<32; c++) outv[c] = 0.f;
  #pragma unroll
  for (int z=0; z<4; z++){
    __syncthreads();
    #pragma unroll
    for (int ms=0; ms<2; ms++)
      #pragma unroll
      for (int ns=0; ns<2; ns++)
        #pragma unroll
        for (int rg=0; rg<4; rg++)
          m32[(wr*32 + ms*16 + kg*4 + rg)*66 + wc*32 + ns*16 + lr] = acc[z][ms][ns][rg];
    __syncthreads();
    if (tid < 128){
      const float* wzT = Wgs + z*1024;
      for (int c2=0; c2<32; c2++){
        float yv = m32[(g*32 + c2)*66 + j];
        const float* wrow = wzT + c2*32;
        #pragma unroll
        for (int c=0; c<32; c++) outv[c] += wrow[c]*yv;
      }
    }
  }
  if (tid < 128 && r0 + g*32 < M){
    int t = (r0 >> 5) + g;
    long ob = ((long)(b*lo + t)*32)*512 + n0 + j;
    #pragma unroll
    for (int c=0; c<32; c++){
      long ofs = ob + (long)c*512;
      xnew[ofs] += outv[c]*BNSCALE;
    }
  }
}

// ---------------- mix1: tconv+act -> fg(split, t-major), base*BNSCALE -> xnew, fgL ----------------
__global__ void k_mix1(const float* __restrict__ x,
    const float* __restrict__ fw, const float* __restrict__ fb,
    const float* __restrict__ gwv, const float* __restrict__ gb,
    const float* __restrict__ gcw, const float* __restrict__ gcb,
    ushort_t* __restrict__ fgh, ushort_t* __restrict__ fgl,
    float* __restrict__ fgL, float* __restrict__ xnew,
    int d, int li, int lo){
  __shared__ float FWs[2048], GWs[2048], W0s[1024];
  __shared__ float fbs[32], gbs[32], gcbs[32];
  int tid = threadIdx.x;
  int t = blockIdx.y, b = blockIdx.z;
  int n = blockIdx.x*256 + tid;
  for (int idx = tid; idx < 2048; idx += 256){ FWs[idx] = fw[idx]; GWs[idx] = gwv[idx]; }
  for (int idx = tid; idx < 1024; idx += 256) W0s[idx] = gcw[(idx>>5)*160 + (idx&31)];
  if (tid < 32){ fbs[tid]=fb[tid]; gbs[tid]=gb[tid]; gcbs[tid]=gcb[tid]; }
  __syncthreads();
  float xv[32], xv2[32], fgv[32];
  const float* xb  = x + ((size_t)(b*li + t)*32)*512 + n;
  const float* xb2 = x + ((size_t)(b*li + t + d)*32)*512 + n;
  #pragma unroll
  for (int c=0;c<32;c++){ xv[c] = xb[(size_t)c*512]; xv2[c] = xb2[(size_t)c*512]; }
  #pragma unroll
  for (int o=0;o<32;o++){
    float f = fbs[o], g = gbs[o];
    #pragma unroll
    for (int c=0;c<32;c++){
      float2 wf = *(const float2*)&FWs[(o*32+c)*2];
      float2 wg = *(const float2*)&GWs[(o*32+c)*2];
      f += xv[c]*wf.x + xv2[c]*wf.y;
      g += xv[c]*wg.x + xv2[c]*wg.y;
    }
    f = fminf(f, 15.f);
    float e2 = __expf(2.f*f);
    float th = (e2 - 1.f)/(e2 + 1.f);
    float sg = 1.f/(1.f + __expf(-g));
    fgv[o] = th*sg;
  }
  size_t rbase = ((size_t)(b*lo + t)*32)*512 + n;
  #pragma unroll
  for (int o=0;o<32;o++){
    float bs = gcbs[o] + xv2[o];
    #pragma unroll
    for (int c=0;c<32;c++) bs += W0s[o*32+c]*fgv[c];
    xnew[rbase + (size_t)o*512] = bs*BNSCALE;
    ushort_t h = f2b(fgv[o]);
    fgh[rbase + (size_t)o*512] = h;
    fgl[rbase + (size_t)o*512] = f2b(fgv[o] - b2f(h));
  }
  if (t == lo-1){
    #pragma unroll
    for (int o=0;o<32;o++) fgL[((size_t)b*32+o)*512 + n] = fgv[o];
  }
}

// ---------------- skip accumulation: 4x s-parallel (512 blocks) ----------------
__global__ void k_skipacc(const float* __restrict__ fgL, const float* __restrict__ sw,
                          const float* __restrict__ sb, float* __restrict__ skip, int init){
  int b = blockIdx.z; int sq = blockIdx.y; int n0 = blockIdx.x*64;
  int tid = threadIdx.x; int col = tid & 63; int q = tid >> 6;
  __shared__ float fgls[32][65];
  for (int idx = tid; idx < 2048; idx += 256){
    int c = idx >> 6, j = idx & 63;
    fgls[c][j] = fgL[((size_t)b*32+c)*512 + n0 + j];
  }
  __syncthreads();
  int s0 = sq*64 + q*16;
  for (int s = s0; s < s0+16; s++){
    float acc = sb[s];
    #pragma unroll
    for (int c = 0; c < 32; c++) acc += sw[s*32+c]*fgls[c][col];
    size_t o = ((size_t)b*256+s)*512 + n0+col;
    skip[o] = init ? acc : skip[o] + acc;
  }
}

// ---------------- end1: tiled GEMM with relu in/out ----------------
__global__ __launch_bounds__(256) void k_end1t(const float* __restrict__ skip,
                        const float* __restrict__ w, const float* __restrict__ bias,
                        float* __restrict__ h){
  int b = blockIdx.z; int e0 = blockIdx.y*32; int n0 = blockIdx.x*64;
  __shared__ float Ws_[32][33];
  __shared__ float Ss_[32][64];
  int tid = threadIdx.x, tx = tid&15, ty = tid>>4;
  float acc[2][4] = {};
  for (int k0 = 0; k0 < 256; k0 += 32){
    for (int q2 = 0; q2 < 4; q2++){ int idx = tid + q2*256; int r = idx>>5, kk = idx&31;
      Ws_[r][kk] = w[(size_t)(e0+r)*256 + k0+kk]; }
    for (int q2 = 0; q2 < 8; q2++){ int idx = tid + q2*256; int r = idx>>6, ww = idx&63;
      Ss_[r][ww] = fmaxf(skip[(size_t)b*131072 + (size_t)(k0+r)*512 + n0+ww], 0.f); }
    __syncthreads();
    #pragma unroll
    for (int kk = 0; kk < 32; kk++){
      float t0 = Ws_[ty][kk], t1 = Ws_[ty+16][kk];
      float4 b4 = *(float4*)&Ss_[kk][tx*4];
      acc[0][0]+=t0*b4.x; acc[0][1]+=t0*b4.y; acc[0][2]+=t0*b4.z; acc[0][3]+=t0*b4.w;
      acc[1][0]+=t1*b4.x; acc[1][1]+=t1*b4.y; acc[1][2]+=t1*b4.z; acc[1][3]+=t1*b4.w;
    }
    __syncthreads();
  }
  for (int i2 = 0; i2 < 2; i2++){
    int e = e0 + ty + 16*i2;
    float bb = bias[e];
    float4 o4 = make_float4(fmaxf(acc[i2][0]+bb,0.f), fmaxf(acc[i2][1]+bb,0.f),
                            fmaxf(acc[i2][2]+bb,0.f), fmaxf(acc[i2][3]+bb,0.f));
    *(float4*)&h[(size_t)b*262144 + (size_t)e*512 + n0 + tx*4] = o4;
  }
}

__global__ void k_end2(const float* __restrict__ h, const float* __restrict__ w,
                       const float* __restrict__ bias, float* __restrict__ out){
  int n = blockIdx.x*256+threadIdx.x; int o=blockIdx.y; int b=blockIdx.z;
  float acc=bias[o];
  const float* hb=h + (size_t)b*262144 + n;
  #pragma unroll 8
  for (int e=0;e<512;e++) acc += w[o*512+e]*hb[(size_t)e*512];
  out[((size_t)b*12+o)*512+n]=acc;
}

extern "C" void kernel_launch(void* const* d_in, const int* in_sizes, int n_in,
                              void* d_out, int out_size, void* d_ws, size_t ws_size,
                              hipStream_t stream) {
  (void)in_sizes; (void)n_in; (void)out_size;
  const float* hist   =(const float*)d_in[0];
  const float* start_w=(const float*)d_in[1];
  const float* start_b=(const float*)d_in[2];
  const float* filt_w =(const float*)d_in[3];
  const float* filt_b =(const float*)d_in[4];
  const float* gate_w =(const float*)d_in[5];
  const float* gate_b =(const float*)d_in[6];
  const float* skip_w =(const float*)d_in[7];
  const float* skip_b =(const float*)d_in[8];
  const float* gconv_w=(const float*)d_in[9];
  const float* gconv_b=(const float*)d_in[10];
  const float* end1_w =(const float*)d_in[11];
  const float* end1_b =(const float*)d_in[12];
  const float* end2_w =(const float*)d_in[13];
  const float* end2_b =(const float*)d_in[14];
  const float* Ex1    =(const float*)d_in[15];
  const float* node1  =(const float*)d_in[16];
  const float* Wd     =(const float*)d_in[17];
  const float* Wxabs  =(const float*)d_in[18];
  const float* TiD    =(const float*)d_in[19];
  const float* DiW    =(const float*)d_in[20];
  const float* nv1    =(const float*)d_in[21];
  const float* nv2    =(const float*)d_in[22];

  char* ws = (char*)d_ws;
  const size_t needed = 83902464;
  if (ws_size < needed) return;

  // ---- persistent layout (bytes) ----
  ushort_t* PtA_hi  = (ushort_t*)(ws + 0);         //   524,288  A^T [m][512]
  ushort_t* PtA_lo  = (ushort_t*)(ws + 524288);
  ushort_t* PtA2_hi = (ushort_t*)(ws + 1048576);   //   524,288  (A^2)^T
  ushort_t* PtA2_lo = (ushort_t*)(ws + 1572864);
  ushort_t* PtB_hi  = (ushort_t*)(ws + 2097152);   // 8,388,608  B^T [b][m][512]
  ushort_t* PtB_lo  = (ushort_t*)(ws + 10485760);
  ushort_t* PtB2_hi = (ushort_t*)(ws + 18874368);  // 8,388,608  (B^2)^T
  ushort_t* PtB2_lo = (ushort_t*)(ws + 27262976);
  float*    stats   = (float*)(ws + 35651584);     // 128
  float*    part    = (float*)(ws + 35651712);     // 2,048 (pad to 16K)
  float*    skip    = (float*)(ws + 35667968);     // 8,388,608
  float*    fgL     = (float*)(ws + 44056576);     // 1,048,576
  ushort_t* fgh     = (ushort_t*)(ws + 45105152);  // 6,291,456  [b][t][c][512]
  ushort_t* fgl     = (ushort_t*)(ws + 51396608);  // 6,291,456
  float*    xA      = (float*)(ws + 57688064);     // 13,631,488 [b][t][c][512] li=13
  float*    xB      = (float*)(ws + 71319552);     // 12,582,912 lo<=12
  // ---- prologue aliases (region [44,056,576 .. 83,902,464) dead during prologue) ----
  float*    gwb     = (float*)(ws + 44056576);     // 1,048,576
  ushort_t* gws_hi  = (ushort_t*)(ws + 45105152);  //   524,288 (A non-T split)
  ushort_t* gws_lo  = (ushort_t*)(ws + 45629440);
  float*    ebuf    = (float*)(ws + 46153728);     // 4,980,736 (dead after k_adp)
  ushort_t* adjh    = (ushort_t*)(ws + 46153728);  // 4,194,304 (over ex-ebuf)
  float*    adp     = (float*)(ws + 51134464);     // 4,194,304
  float*    xw      = (float*)(ws + 55328768);     // 4,194,304
  float*    adjb    = (float*)(ws + 59523072);     // 16,777,216
  ushort_t* adjl    = (ushort_t*)(ws + 76300288);  // 4,194,304
  // ---- epilogue alias (fg/x dead after layer loop) ----
  float*    hbuf    = (float*)(ws + 45105152);     // 16,777,216

  // ======== prologue: adjacency supports ========
  k_embed<<<dim3(8192),dim3(64),0,stream>>>(hist,Ex1,node1,TiD,DiW,ebuf);
  k_adp<<<dim3(512),dim3(128),0,stream>>>(ebuf,Wd,adp);          // ebuf dead after this
  k_gw_mm<<<dim3(1024),dim3(256),0,stream>>>(nv1,nv2,gwb);
  k_gw_sm<<<dim3(512),dim3(256),0,stream>>>(gwb, gws_hi, gws_lo);
  k_splitT<<<dim3(16,16,1),dim3(256),0,stream>>>(gwb, 0, PtA_hi, 0, 512, PtA_lo, 0, 512);
  // A^2 power: (A^T)^2 -> PtA2 (split-write)
  k_pow<<<dim3(8,8,1),dim3(256),0,stream>>>(
      PtA_hi, PtA_lo, 0, gws_hi, gws_lo, 0, PtA2_hi, PtA2_lo, 0);
  k_lnp1<<<dim3(256),dim3(256),0,stream>>>(adp,part);
  k_lnp2<<<dim3(1),dim3(256),0,stream>>>(part,stats);
  k_xw<<<dim3(8192),dim3(128),0,stream>>>(adp,Wxabs,stats,xw);
  k_adjmm<<<dim3(8,16,16),dim3(256),0,stream>>>(xw,adp,stats,adjb);
  k_topk<<<dim3(8192),dim3(64),0,stream>>>(adjb, adjh, adjl);
  k_splitT<<<dim3(16,16,16),dim3(256),0,stream>>>(adjb, 262144, PtB_hi, 262144, 512,
                                                  PtB_lo, 262144, 512);
  // B^2 power per batch: (B^T)^2 -> PtB2 (split-write)
  k_pow<<<dim3(8,8,16),dim3(256),0,stream>>>(
      PtB_hi, PtB_lo, 262144, adjh, adjl, 262144, PtB2_hi, PtB2_lo, 262144);

  k_start<<<dim3(13312),dim3(256),0,stream>>>(hist,start_w,start_b,xA);

  // ======== layer loop ========
  const int lin[8]={13,12,10,9,7,6,4,3};
  const int dil[8]={1,2,1,2,1,2,1,2};
  float* xcur=xA; float* alt=xB;
  for (int i=0;i<8;i++){
    int d=dil[i], li=lin[i], lo=li-d;
    const float* fwp=filt_w+(size_t)i*2048; const float* fbp=filt_b+i*32;
    const float* gwp=gate_w+(size_t)i*2048; const float* gbp=gate_b+i*32;
    const float* swp=skip_w+(size_t)i*8192; const float* sbp=skip_b+i*256;
    const float* gcwp=gconv_w+(size_t)i*5120; const float* gcbp=gconv_b+i*32;
    int M = 32*lo, Mt = (M+63)/64;

    k_mix1<<<dim3(2,lo,16),dim3(256),0,stream>>>(xcur,fwp,fbp,gwp,gbp,gcwp,gcbp,
        fgh,fgl,fgL,alt,d,li,lo);
    k_skipacc<<<dim3(8,4,16),dim3(256),0,stream>>>(fgL,swp,sbp,skip,(i==0)?1:0);

    if (i < 7){
      k_gemms<<<dim3(Mt*8*16),dim3(256),0,stream>>>(
          fgh, fgl,
          PtA_hi, PtA_lo, PtA2_hi, PtA2_lo, PtB_hi, PtB_lo, PtB2_hi, PtB2_lo,
          gcwp, alt, Mt, M, lo);
    }
    float* tmp=xcur; xcur=alt; alt=tmp;
  }

  // ======== head ========
  k_end1t<<<dim3(8,16,16),dim3(256),0,stream>>>(skip,end1_w,end1_b,hbuf);
  k_end2<<<dim3(2,12,16),dim3(256),0,stream>>>(hbuf,end2_w,end2_b,(float*)d_out);
}

// Round 20
// 1204.243 us; speedup vs baseline: 1.8951x; 1.0103x over previous
//
#include <hip/hip_runtime.h>
#include <cstdint>
#include <math.h>

typedef unsigned short ushort_t;
typedef __bf16 bf16x8 __attribute__((ext_vector_type(8)));
typedef float f32x4 __attribute__((ext_vector_type(4)));

#define BNSCALE 0.9999950000374998f

__device__ __forceinline__ ushort_t f2b(float x){
  union { float f; uint32_t u; } v; v.f = x;
  uint32_t u = v.u;
  u = u + 0x7fffu + ((u >> 16) & 1u);
  return (ushort_t)(u >> 16);
}
__device__ __forceinline__ float b2f(ushort_t h){
  union { float f; uint32_t u; } v; v.u = ((uint32_t)h) << 16; return v.f;
}

__device__ __forceinline__ uint32_t rotl32(uint32_t x, int d){ return (x<<d)|(x>>(32-d)); }

__device__ __forceinline__ void threefry2x32(uint32_t& x0, uint32_t& x1){
  const uint32_t ks0=0u, ks1=42u, ks2=42u^0x1BD11BDAu;
  x0+=ks0; x1+=ks1;
  x0+=x1; x1=rotl32(x1,13); x1^=x0;
  x0+=x1; x1=rotl32(x1,15); x1^=x0;
  x0+=x1; x1=rotl32(x1,26); x1^=x0;
  x0+=x1; x1=rotl32(x1, 6); x1^=x0;
  x0+=ks1; x1+=ks2+1u;
  x0+=x1; x1=rotl32(x1,17); x1^=x0;
  x0+=x1; x1=rotl32(x1,29); x1^=x0;
  x0+=x1; x1=rotl32(x1,16); x1^=x0;
  x0+=x1; x1=rotl32(x1,24); x1^=x0;
  x0+=ks2; x1+=ks0+2u;
  x0+=x1; x1=rotl32(x1,13); x1^=x0;
  x0+=x1; x1=rotl32(x1,15); x1^=x0;
  x0+=x1; x1=rotl32(x1,26); x1^=x0;
  x0+=x1; x1=rotl32(x1, 6); x1^=x0;
  x0+=ks0; x1+=ks1+3u;
  x0+=x1; x1=rotl32(x1,17); x1^=x0;
  x0+=x1; x1=rotl32(x1,29); x1^=x0;
  x0+=x1; x1=rotl32(x1,16); x1^=x0;
  x0+=x1; x1=rotl32(x1,24); x1^=x0;
  x0+=ks1; x1+=ks2+4u;
  x0+=x1; x1=rotl32(x1,13); x1^=x0;
  x0+=x1; x1=rotl32(x1,15); x1^=x0;
  x0+=x1; x1=rotl32(x1,26); x1^=x0;
  x0+=x1; x1=rotl32(x1, 6); x1^=x0;
  x0+=ks2; x1+=ks0+5u;
}

// ---------------- fused nodevec graph: mm + softmax + split ----------------
__global__ void k_gw(const float* __restrict__ nv1, const float* __restrict__ nv2,
                     float* __restrict__ gw, ushort_t* __restrict__ hi,
                     ushort_t* __restrict__ lo){
  int v = blockIdx.x; int tid = threadIdx.x;
  float d0 = 0.f, d1 = 0.f;
  #pragma unroll
  for (int k = 0; k < 64; k++){
    float nk = nv1[v*64+k];
    d0 += nk*nv2[k*512 + tid];
    d1 += nk*nv2[k*512 + 256 + tid];
  }
  float a0 = fmaxf(d0, 0.f), a1 = fmaxf(d1, 0.f);
  __shared__ float red[256];
  red[tid]=fmaxf(a0,a1); __syncthreads();
  for(int s=128;s>0;s>>=1){ if(tid<s) red[tid]=fmaxf(red[tid],red[tid+s]); __syncthreads(); }
  float m = red[0]; __syncthreads();
  float e0=expf(a0-m), e1=expf(a1-m);
  red[tid]=e0+e1; __syncthreads();
  for(int s=128;s>0;s>>=1){ if(tid<s) red[tid]+=red[tid+s]; __syncthreads(); }
  float inv = 1.0f/red[0];
  float v0 = e0*inv, v1 = e1*inv;
  gw[v*512+tid]=v0; gw[v*512+256+tid]=v1;
  ushort_t h0 = f2b(v0);
  hi[v*512+tid] = h0; lo[v*512+tid] = f2b(v0 - b2f(h0));
  ushort_t h1 = f2b(v1);
  hi[v*512+256+tid] = h1; lo[v*512+256+tid] = f2b(v1 - b2f(h1));
}

// ---------------- embedding (exact 12-pt DFT twiddles) ----------------
__global__ void k_embed(const float* __restrict__ hist, const float* __restrict__ Ex1,
                        const float* __restrict__ node1, const float* __restrict__ TiD,
                        const float* __restrict__ DiW, float* __restrict__ e){
  const float c12[12] = {1.f, 0.8660254037844387f, 0.5f, 0.f, -0.5f, -0.8660254037844387f,
                         -1.f, -0.8660254037844387f, -0.5f, 0.f, 0.5f, 0.8660254037844387f};
  const float s12[12] = {0.f, -0.5f, -0.8660254037844387f, -1.f, -0.8660254037844387f, -0.5f,
                         0.f, 0.5f, 0.8660254037844387f, 1.f, 0.8660254037844387f, 0.5f};
  int row = blockIdx.x; int b = row >> 9; int n = row & 511;
  int tid = threadIdx.x;
  __shared__ float fr[7];
  if (tid < 7){
    float re=0.f, im=0.f;
    for (int l=0;l<12;l++){
      float v = hist[((size_t)(b*12+l)*512+n)*3];
      int idx = (tid*l) % 12;
      re += v*c12[idx]; im += v*s12[idx];
    }
    fr[tid]=sqrtf(re*re+im*im);
  }
  __syncthreads();
  float* er = e + (size_t)row*152;
  float acc=0.f;
  #pragma unroll
  for (int f=0;f<7;f++) acc += fr[f]*Ex1[f*64+tid];
  er[tid]=acc;
  er[64+tid]=node1[n*64+tid];
  if (tid<12){
    int it = (int)(hist[((size_t)(b*12+11)*512+n)*3+1]*288.0f);
    int id = (int)(hist[((size_t)(b*12+11)*512+n)*3+2]*7.0f);
    er[128+tid]=TiD[it*12+tid];
    er[140+tid]=DiW[id*12+tid];
  }
}

// ---------------- adp = e @ Wd[n] (Wd read once) ----------------
__global__ void k_adp(const float* __restrict__ e, const float* __restrict__ Wd,
                      float* __restrict__ adp){
  int n = blockIdx.x; int tid = threadIdx.x; // 128 threads
  __shared__ float es[16][152];
  for (int idx = tid; idx < 16*152; idx += 128){
    int r = idx / 152, q = idx - r*152;
    es[r][q] = e[((size_t)(r*512+n))*152 + q];
  }
  __syncthreads();
  const float* w = Wd + (size_t)n*152*128;
  float acc[16];
  #pragma unroll
  for (int r=0;r<16;r++) acc[r]=0.f;
  for (int q = 0; q < 152; q++){
    float wv = w[q*128 + tid];
    #pragma unroll
    for (int r = 0; r < 16; r++) acc[r] += es[r][q]*wv;
  }
  #pragma unroll
  for (int r=0;r<16;r++) adp[((size_t)(r*512+n))*128 + tid] = acc[r];
}

// ---------------- layernorm stats, two-stage ----------------
__global__ void k_lnp1(const float* __restrict__ adp, float* __restrict__ part){
  int blk = blockIdx.x; int tid = threadIdx.x;
  const float* p = adp + (size_t)(blk>>4)*65536 + (size_t)(blk&15)*4096;
  float s=0.f, s2=0.f;
  for (int i=tid;i<4096;i+=256){ float v=p[i]; s+=v; s2+=v*v; }
  __shared__ float rs[256], rs2[256];
  rs[tid]=s; rs2[tid]=s2; __syncthreads();
  for(int k=128;k>0;k>>=1){ if(tid<k){rs[tid]+=rs[tid+k]; rs2[tid]+=rs2[tid+k];} __syncthreads(); }
  if(tid==0){ part[blk*2]=rs[0]; part[blk*2+1]=rs2[0]; }
}

__global__ void k_lnp2(const float* __restrict__ part, float* __restrict__ stats){
  int tid = threadIdx.x; // 256
  int b = tid >> 4, c = tid & 15;
  float s = part[tid*2], s2 = part[tid*2+1];
  #pragma unroll
  for (int off=8; off>=1; off>>=1){ s += __shfl_down(s,off); s2 += __shfl_down(s2,off); }
  if (c==0){
    float mu = s/65536.f; float var = s2/65536.f - mu*mu;
    stats[b*2]=mu; stats[b*2+1]=rsqrtf(var+1e-8f);
  }
}

// ---------------- t = norm(adp) @ Wxabs ----------------
__global__ void k_xw(const float* __restrict__ adp, const float* __restrict__ Wx,
                     const float* __restrict__ stats, float* __restrict__ t){
  int row=blockIdx.x; int tid=threadIdx.x; int b=row>>9;
  __shared__ float as[128];
  as[tid]=(adp[(size_t)row*128+tid]-stats[2*b])*stats[2*b+1];
  __syncthreads();
  float acc=0.f;
  #pragma unroll 8
  for(int k=0;k<128;k++) acc += as[k]*Wx[k*128+tid];
  t[(size_t)row*128+tid]=acc;
}

// ---------------- adj = relu(t @ norm(adp)^T) ----------------
__global__ __launch_bounds__(256) void k_adjmm(const float* __restrict__ T,
                        const float* __restrict__ P, const float* __restrict__ stats,
                        float* __restrict__ adj){
  int b = blockIdx.z;
  int n0 = blockIdx.y*32, m0 = blockIdx.x*64;
  const float* Tb = T + (size_t)b*512*128;
  const float* Pb = P + (size_t)b*512*128;
  float mu = stats[2*b], isig = stats[2*b+1];
  __shared__ float Ts[32][33];
  __shared__ float Ps[64][33];
  int tid=threadIdx.x; int tx=tid&15, ty=tid>>4;
  float acc[2][4]={};
  for(int k0=0;k0<128;k0+=32){
    for(int q=0;q<4;q++){ int idx=tid+q*256; int r=idx>>5, kk=idx&31; Ts[r][kk]=Tb[(size_t)(n0+r)*128+k0+kk]; }
    for(int q=0;q<8;q++){ int idx=tid+q*256; int r=idx>>5, kk=idx&31; Ps[r][kk]=(Pb[(size_t)(m0+r)*128+k0+kk]-mu)*isig; }
    __syncthreads();
    #pragma unroll
    for(int kk=0;kk<32;kk++){
      float t0=Ts[ty][kk], t1=Ts[ty+16][kk];
      float p0=Ps[tx*4+0][kk], p1=Ps[tx*4+1][kk], p2=Ps[tx*4+2][kk], p3=Ps[tx*4+3][kk];
      acc[0][0]+=t0*p0; acc[0][1]+=t0*p1; acc[0][2]+=t0*p2; acc[0][3]+=t0*p3;
      acc[1][0]+=t1*p0; acc[1][1]+=t1*p1; acc[1][2]+=t1*p2; acc[1][3]+=t1*p3;
    }
    __syncthreads();
  }
  for(int i2=0;i2<2;i2++){
    int n=n0+ty+16*i2;
    float4 o4=make_float4(fmaxf(acc[i2][0],0.f),fmaxf(acc[i2][1],0.f),
                          fmaxf(acc[i2][2],0.f),fmaxf(acc[i2][3],0.f));
    *(float4*)&adj[((size_t)b*512+n)*512+m0+tx*4]=o4;
  }
}

// ---------------- top-20 + mask + softmax*0.5, fused split-bf16 write ----------------
__global__ void k_topk(float* __restrict__ adj, ushort_t* __restrict__ adjh,
                       ushort_t* __restrict__ adjl){
  const int row = blockIdx.x;
  const int tid = threadIdx.x;
  const uint32_t halfn = 2097152u;
  float a[8], v[8];
  const bool lowhalf = row < 4096;
  #pragma unroll
  for(int k=0;k<8;k++){
    int m = k*64+tid;
    uint32_t i = (uint32_t)row*512u + (uint32_t)m;
    uint32_t c0 = lowhalf ? i : i - halfn;
    uint32_t x0=c0, x1=c0+halfn;
    threefry2x32(x0,x1);
    uint32_t bits = lowhalf ? x0 : x1;
    float u = __uint_as_float((bits>>9)|0x3f800000u)-1.0f;
    a[k]=adj[(size_t)row*512+m];
    v[k]=a[k]+0.01f*u;
  }
  unsigned selmask=0u;
  for(int it=0; it<20; it++){
    float best=-1e30f; int bi=0x7fffffff;
    #pragma unroll
    for(int k=0;k<8;k++){
      if(!((selmask>>k)&1u)){
        int m=k*64+tid;
        if(v[k]>best || (v[k]==best && m<bi)){best=v[k]; bi=m;}
      }
    }
    #pragma unroll
    for(int off=32; off>=1; off>>=1){
      float ov=__shfl_xor(best,off); int oi=__shfl_xor(bi,off);
      if(ov>best || (ov==best && oi<bi)){best=ov; bi=oi;}
    }
    if((bi&63)==tid) selmask |= 1u<<(bi>>6);
  }
  float M=0.f;
  #pragma unroll
  for(int k=0;k<8;k++) if((selmask>>k)&1u) M=fmaxf(M,a[k]);
  #pragma unroll
  for(int off=32;off>=1;off>>=1) M=fmaxf(M,__shfl_xor(M,off));
  float S=0.f;
  #pragma unroll
  for(int k=0;k<8;k++) S += expf((((selmask>>k)&1u)? a[k]:0.f) - M);
  #pragma unroll
  for(int off=32;off>=1;off>>=1) S += __shfl_xor(S,off);
  float inv = 0.5f/S;
  #pragma unroll
  for(int k=0;k<8;k++){
    int m=k*64+tid;
    float val = expf((((selmask>>k)&1u)? a[k]:0.f)-M)*inv;
    size_t o = (size_t)row*512+m;
    adj[o] = val;
    ushort_t h = f2b(val);
    adjh[o] = h;
    adjl[o] = f2b(val - b2f(h));
  }
}

// ---------------- fp32 -> split bf16 with transpose (per batch) ----------------
__global__ void k_splitT(const float* __restrict__ src, long sBS,
                         ushort_t* __restrict__ hi, long hBS, int hRS,
                         ushort_t* __restrict__ lo, long lBS, int lRS){
  int b = blockIdx.z;
  int c0 = blockIdx.x*32, r0 = blockIdx.y*32;
  __shared__ float tile[32][33];
  int tx = threadIdx.x & 31, ty = threadIdx.x >> 5;
  for (int q = 0; q < 4; q++)
    tile[ty+q*8][tx] = src[b*sBS + (size_t)(r0+ty+q*8)*512 + c0+tx];
  __syncthreads();
  for (int q = 0; q < 4; q++){
    int cc = c0+ty+q*8, rr = r0+tx;
    float v = tile[tx][ty+q*8];
    ushort_t h = f2b(v);
    hi[b*hBS + (size_t)cc*hRS + rr] = h;
    lo[b*lBS + (size_t)cc*lRS + rr] = f2b(v - b2f(h));
  }
}

// ---------------- k_pow: 64x64-tile split-bf16 power GEMM, split write ----------------
__global__ __launch_bounds__(256,2) void k_pow(
    const ushort_t* __restrict__ Ah, const ushort_t* __restrict__ Al, long aBS,
    const ushort_t* __restrict__ Bh, const ushort_t* __restrict__ Bl, long bBS,
    ushort_t* __restrict__ Ch, ushort_t* __restrict__ Cl, long cBS){
  __shared__ __align__(16) ushort_t At[5120];  // hi [64][40], lo at +2560
  __shared__ __align__(16) ushort_t Bt[5120];
  const int b = blockIdx.z;
  const int r0 = blockIdx.x*64, n0 = blockIdx.y*64;
  const int tid = threadIdx.x;
  const int w = tid >> 6, l = tid & 63, lr = l & 15, kg = l >> 4;
  const int wr = w & 1, wc = w >> 1;
  const int ra = tid >> 2, ca = (tid & 3)*8;
  const ushort_t* Ahp = Ah + (long)b*aBS + (long)(r0+ra)*512 + ca;
  const ushort_t* Alp = Al + (long)b*aBS + (long)(r0+ra)*512 + ca;
  const ushort_t* Bhp = Bh + (long)b*bBS + (long)(n0+ra)*512 + ca;
  const ushort_t* Blp = Bl + (long)b*bBS + (long)(n0+ra)*512 + ca;
  f32x4 acc[2][2];
  #pragma unroll
  for (int ms=0; ms<2; ms++)
    #pragma unroll
    for (int ns=0; ns<2; ns++) acc[ms][ns] = (f32x4){0.f,0.f,0.f,0.f};
  uint4 pA0,pA1,pB0,pB1;
  #define LDP(K0) { \
    pA0 = *(const uint4*)(Ahp + (K0)); pA1 = *(const uint4*)(Alp + (K0)); \
    pB0 = *(const uint4*)(Bhp + (K0)); pB1 = *(const uint4*)(Blp + (K0)); }
  LDP(0);
  for (int k0 = 0; k0 < 512; k0 += 32){
    __syncthreads();
    *(uint4*)&At[ra*40 + ca]        = pA0;
    *(uint4*)&At[2560 + ra*40 + ca] = pA1;
    *(uint4*)&Bt[ra*40 + ca]        = pB0;
    *(uint4*)&Bt[2560 + ra*40 + ca] = pB1;
    __syncthreads();
    if (k0 + 32 < 512) LDP(k0 + 32);
    bf16x8 ahv[2], alv[2], bhv[2], blv[2];
    #pragma unroll
    for (int ms=0; ms<2; ms++){
      int ar = wr*32 + ms*16 + lr;
      ahv[ms] = *(const bf16x8*)&At[ar*40 + kg*8];
      alv[ms] = *(const bf16x8*)&At[2560 + ar*40 + kg*8];
    }
    #pragma unroll
    for (int ns=0; ns<2; ns++){
      int br = wc*32 + ns*16 + lr;
      bhv[ns] = *(const bf16x8*)&Bt[br*40 + kg*8];
      blv[ns] = *(const bf16x8*)&Bt[2560 + br*40 + kg*8];
    }
    #pragma unroll
    for (int ms=0; ms<2; ms++)
      #pragma unroll
      for (int ns=0; ns<2; ns++){
        acc[ms][ns] = __builtin_amdgcn_mfma_f32_16x16x32_bf16(ahv[ms], bhv[ns], acc[ms][ns], 0, 0, 0);
        acc[ms][ns] = __builtin_amdgcn_mfma_f32_16x16x32_bf16(alv[ms], bhv[ns], acc[ms][ns], 0, 0, 0);
        acc[ms][ns] = __builtin_amdgcn_mfma_f32_16x16x32_bf16(ahv[ms], blv[ns], acc[ms][ns], 0, 0, 0);
      }
  }
  #undef LDP
  #pragma unroll
  for (int ms=0; ms<2; ms++)
    #pragma unroll
    for (int rg=0; rg<4; rg++){
      int r = r0 + wr*32 + ms*16 + kg*4 + rg;
      #pragma unroll
      for (int ns=0; ns<2; ns++){
        int n = n0 + wc*32 + ns*16 + lr;
        float v = acc[ms][ns][rg];
        long ofs = (long)b*cBS + (long)r*512 + n;
        ushort_t hv = f2b(v);
        Ch[ofs] = hv;
        Cl[ofs] = f2b(v - b2f(hv));
      }
    }
}

// ---------------- layer GEMM: 64x64 tile, 4 zones INSIDE K-loop (round-14 proven) ----------------
__global__ __launch_bounds__(256,1) void k_gemms(
    const ushort_t* __restrict__ Afh, const ushort_t* __restrict__ Afl,
    const ushort_t* __restrict__ S0h, const ushort_t* __restrict__ S0l,
    const ushort_t* __restrict__ S1h, const ushort_t* __restrict__ S1l,
    const ushort_t* __restrict__ S2h, const ushort_t* __restrict__ S2l,
    const ushort_t* __restrict__ S3h, const ushort_t* __restrict__ S3l,
    const float* __restrict__ gcw, float* __restrict__ xnew,
    int Mt, int M, int lo){
  __shared__ __align__(16) char smem[51200];
  ushort_t* At = (ushort_t*)smem;              // hi [64][40] (5120B), lo at +2560 ush
  ushort_t* Bt = (ushort_t*)(smem + 10240);    // zone z at +z*5120 ush {hi, lo at +2560}
  float* m32 = (float*)smem;                   // epilogue: [64][66] f32 (16896B)
  float* Wgs = (float*)(smem + 16896);         // epilogue: [4][32 c2][32 c] (16384B)
  // XCD-chunked swizzle
  const int total = gridDim.x;
  const int chunk = total >> 3;
  const int lid = blockIdx.x;
  const int swz = (lid & 7)*chunk + (lid >> 3);
  const int x = swz % Mt;
  const int rest = swz / Mt;
  const int y = rest & 7;
  const int b = rest >> 3;
  const int n0 = y*64, r0 = x*64;
  const int tid = threadIdx.x;
  const int w = tid >> 6, l = tid & 63, lr = l & 15, kg = l >> 4;
  const int wr = w & 1, wc = w >> 1;
  // A staging: row ra = tid>>2, 8-ushort chunk ca
  const int ra = tid >> 2, ca = (tid & 3)*8;
  int arow = r0 + ra; if (arow >= M) arow = M - 1;
  const ushort_t* Ahp = Afh + (long)b*M*512 + (long)arow*512 + ca;
  const ushort_t* Alp = Afl + (long)b*M*512 + (long)arow*512 + ca;
  // B staging: zone zz = tid>>6, row rb = tid&63 (full 32-ushort row, hi+lo)
  const int zz = tid >> 6, rb = tid & 63;
  const ushort_t* Bz; const ushort_t* Bzl;
  if (zz == 0){ Bz = S0h; Bzl = S0l; }
  else if (zz == 1){ Bz = S1h; Bzl = S1l; }
  else if (zz == 2){ Bz = S2h + (long)b*262144; Bzl = S2l + (long)b*262144; }
  else { Bz = S3h + (long)b*262144; Bzl = S3l + (long)b*262144; }
  const ushort_t* Bhp = Bz + (long)(n0 + rb)*512;
  const ushort_t* Blp = Bzl + (long)(n0 + rb)*512;

  f32x4 acc[4][2][2];
  #pragma unroll
  for (int z=0; z<4; z++)
    #pragma unroll
    for (int ms=0; ms<2; ms++)
      #pragma unroll
      for (int ns=0; ns<2; ns++) acc[z][ms][ns] = (f32x4){0.f,0.f,0.f,0.f};

  uint4 pA0,pA1,pB0,pB1,pB2,pB3,pB4,pB5,pB6,pB7;
  #define LDG(K0) { \
    pA0 = *(const uint4*)(Ahp + (K0)); pA1 = *(const uint4*)(Alp + (K0)); \
    pB0 = *(const uint4*)(Bhp + (K0));      pB1 = *(const uint4*)(Bhp + (K0) + 8); \
    pB2 = *(const uint4*)(Bhp + (K0) + 16); pB3 = *(const uint4*)(Bhp + (K0) + 24); \
    pB4 = *(const uint4*)(Blp + (K0));      pB5 = *(const uint4*)(Blp + (K0) + 8); \
    pB6 = *(const uint4*)(Blp + (K0) + 16); pB7 = *(const uint4*)(Blp + (K0) + 24); }
  LDG(0);
  for (int k0 = 0; k0 < 512; k0 += 32){
    __syncthreads();
    *(uint4*)&At[ra*40 + ca]        = pA0;
    *(uint4*)&At[2560 + ra*40 + ca] = pA1;
    {
      ushort_t* bb = Bt + zz*5120 + rb*40;
      *(uint4*)&bb[0]  = pB0; *(uint4*)&bb[8]  = pB1;
      *(uint4*)&bb[16] = pB2; *(uint4*)&bb[24] = pB3;
      ushort_t* bl2 = bb + 2560;
      *(uint4*)&bl2[0]  = pB4; *(uint4*)&bl2[8]  = pB5;
      *(uint4*)&bl2[16] = pB6; *(uint4*)&bl2[24] = pB7;
    }
    __syncthreads();
    if (k0 + 32 < 512) LDG(k0 + 32);
    bf16x8 ahv[2], alv[2];
    #pragma unroll
    for (int ms=0; ms<2; ms++){
      int ar = wr*32 + ms*16 + lr;
      ahv[ms] = *(const bf16x8*)&At[ar*40 + kg*8];
      alv[ms] = *(const bf16x8*)&At[2560 + ar*40 + kg*8];
    }
    #pragma unroll
    for (int z=0; z<4; z++){
      #pragma unroll
      for (int ns=0; ns<2; ns++){
        int br = wc*32 + ns*16 + lr;
        bf16x8 bh = *(const bf16x8*)&Bt[z*5120 + br*40 + kg*8];
        bf16x8 bl = *(const bf16x8*)&Bt[z*5120 + 2560 + br*40 + kg*8];
        #pragma unroll
        for (int ms=0; ms<2; ms++){
          acc[z][ms][ns] = __builtin_amdgcn_mfma_f32_16x16x32_bf16(ahv[ms], bh, acc[z][ms][ns], 0, 0, 0);
          acc[z][ms][ns] = __builtin_amdgcn_mfma_f32_16x16x32_bf16(alv[ms], bh, acc[z][ms][ns], 0, 0, 0);
          acc[z][ms][ns] = __builtin_amdgcn_mfma_f32_16x16x32_bf16(ahv[ms], bl, acc[z][ms][ns], 0, 0, 0);
        }
      }
    }
  }
  #undef LDG
  // ---- epilogue: Wgs(T) load, then per-zone LDS round-trip + channel mix ----
  __syncthreads();
  for (int idx = tid; idx < 4096; idx += 256){
    int z = idx >> 10, rem = idx & 1023;
    int c2 = rem >> 5, c = rem & 31;
    Wgs[idx] = gcw[c*160 + (z+1)*32 + c2];     // transposed: [z][c2][c]
  }
  const int g = tid >> 6, j = tid & 63;   // active threads: tid<128 -> (g in {0,1}, j)
  float outv[32];
  #pragma unroll
  for (int c=0; c<32; c++) outv[c] = 0.f;
  #pragma unroll
  for (int z=0; z<4; z++){
    __syncthreads();
    #pragma unroll
    for (int ms=0; ms<2; ms++)
      #pragma unroll
      for (int ns=0; ns<2; ns++)
        #pragma unroll
        for (int rg=0; rg<4; rg++)
          m32[(wr*32 + ms*16 + kg*4 + rg)*66 + wc*32 + ns*16 + lr] = acc[z][ms][ns][rg];
    __syncthreads();
    if (tid < 128){
      const float* wzT = Wgs + z*1024;
      for (int c2=0; c2<32; c2++){
        float yv = m32[(g*32 + c2)*66 + j];
        const float* wrow = wzT + c2*32;
        #pragma unroll
        for (int c=0; c<32; c++) outv[c] += wrow[c]*yv;
      }
    }
  }
  if (tid < 128 && r0 + g*32 < M){
    int t = (r0 >> 5) + g;
    long ob = ((long)(b*lo + t)*32)*512 + n0 + j;
    #pragma unroll
    for (int c=0; c<32; c++){
      long ofs = ob + (long)c*512;
      xnew[ofs] += outv[c]*BNSCALE;
    }
  }
}

// ---------------- mix1: tconv+act -> fg(split, t-major), base*BNSCALE -> xnew, fgL ----------------
// layer0: compute x on the fly from hist + start conv (k_start folded in).
__global__ void k_mix1(const float* __restrict__ x,
    const float* __restrict__ hist, const float* __restrict__ stw,
    const float* __restrict__ stb, int layer0,
    const float* __restrict__ fw, const float* __restrict__ fb,
    const float* __restrict__ gwv, const float* __restrict__ gb,
    const float* __restrict__ gcw, const float* __restrict__ gcb,
    ushort_t* __restrict__ fgh, ushort_t* __restrict__ fgl,
    float* __restrict__ fgL, float* __restrict__ xnew,
    int d, int li, int lo){
  __shared__ float FWs[2048], GWs[2048], W0s[1024];
  __shared__ float fbs[32], gbs[32], gcbs[32], sws[64], sbs[32];
  int tid = threadIdx.x;
  int t = blockIdx.y, b = blockIdx.z;
  int n = blockIdx.x*256 + tid;
  for (int idx = tid; idx < 2048; idx += 256){ FWs[idx] = fw[idx]; GWs[idx] = gwv[idx]; }
  for (int idx = tid; idx < 1024; idx += 256) W0s[idx] = gcw[(idx>>5)*160 + (idx&31)];
  if (tid < 32){ fbs[tid]=fb[tid]; gbs[tid]=gb[tid]; gcbs[tid]=gcb[tid]; }
  if (layer0){
    if (tid < 64) sws[tid] = stw[tid];
    if (tid >= 64 && tid < 96) sbs[tid-64] = stb[tid-64];
  }
  __syncthreads();
  float xv[32], xv2[32], fgv[32];
  if (layer0){
    // x[b][t][o][n] = sb[o] + h0*sw[o*2] + h1*sw[o*2+1], h from hist[b][t-1][n], 0 at t==0.
    float h0a = 0.f, h1a = 0.f;
    if (t > 0){
      const float* h = hist + ((size_t)(b*12 + (t-1))*512 + n)*3;
      h0a = h[0]; h1a = h[1];
    }
    const float* h2 = hist + ((size_t)(b*12 + t)*512 + n)*3;   // (t+d)-1 = t for d=1
    float h0b = h2[0], h1b = h2[1];
    #pragma unroll
    for (int c=0;c<32;c++){
      xv[c]  = sbs[c] + h0a*sws[c*2] + h1a*sws[c*2+1];
      xv2[c] = sbs[c] + h0b*sws[c*2] + h1b*sws[c*2+1];
    }
  } else {
    const float* xb  = x + ((size_t)(b*li + t)*32)*512 + n;
    const float* xb2 = x + ((size_t)(b*li + t + d)*32)*512 + n;
    #pragma unroll
    for (int c=0;c<32;c++){ xv[c] = xb[(size_t)c*512]; xv2[c] = xb2[(size_t)c*512]; }
  }
  #pragma unroll
  for (int o=0;o<32;o++){
    float f = fbs[o], g = gbs[o];
    #pragma unroll
    for (int c=0;c<32;c++){
      float2 wf = *(const float2*)&FWs[(o*32+c)*2];
      float2 wg = *(const float2*)&GWs[(o*32+c)*2];
      f += xv[c]*wf.x + xv2[c]*wf.y;
      g += xv[c]*wg.x + xv2[c]*wg.y;
    }
    f = fminf(f, 15.f);
    float e2 = __expf(2.f*f);
    float th = (e2 - 1.f)/(e2 + 1.f);
    float sg = 1.f/(1.f + __expf(-g));
    fgv[o] = th*sg;
  }
  size_t rbase = ((size_t)(b*lo + t)*32)*512 + n;
  #pragma unroll
  for (int o=0;o<32;o++){
    float bs = gcbs[o] + xv2[o];
    #pragma unroll
    for (int c=0;c<32;c++) bs += W0s[o*32+c]*fgv[c];
    xnew[rbase + (size_t)o*512] = bs*BNSCALE;
    ushort_t h = f2b(fgv[o]);
    fgh[rbase + (size_t)o*512] = h;
    fgl[rbase + (size_t)o*512] = f2b(fgv[o] - b2f(h));
  }
  if (t == lo-1){
    #pragma unroll
    for (int o=0;o<32;o++) fgL[((size_t)b*32+o)*512 + n] = fgv[o];
  }
}

// ---------------- skip accumulation: 4x s-parallel (512 blocks) ----------------
__global__ void k_skipacc(const float* __restrict__ fgL, const float* __restrict__ sw,
                          const float* __restrict__ sb, float* __restrict__ skip, int init){
  int b = blockIdx.z; int sq = blockIdx.y; int n0 = blockIdx.x*64;
  int tid = threadIdx.x; int col = tid & 63; int q = tid >> 6;
  __shared__ float fgls[32][65];
  for (int idx = tid; idx < 2048; idx += 256){
    int c = idx >> 6, j = idx & 63;
    fgls[c][j] = fgL[((size_t)b*32+c)*512 + n0 + j];
  }
  __syncthreads();
  int s0 = sq*64 + q*16;
  for (int s = s0; s < s0+16; s++){
    float acc = sb[s];
    #pragma unroll
    for (int c = 0; c < 32; c++) acc += sw[s*32+c]*fgls[c][col];
    size_t o = ((size_t)b*256+s)*512 + n0+col;
    skip[o] = init ? acc : skip[o] + acc;
  }
}

// ---------------- end1: tiled GEMM with relu in/out ----------------
__global__ __launch_bounds__(256) void k_end1t(const float* __restrict__ skip,
                        const float* __restrict__ w, const float* __restrict__ bias,
                        float* __restrict__ h){
  int b = blockIdx.z; int e0 = blockIdx.y*32; int n0 = blockIdx.x*64;
  __shared__ float Ws_[32][33];
  __shared__ float Ss_[32][64];
  int tid = threadIdx.x, tx = tid&15, ty = tid>>4;
  float acc[2][4] = {};
  for (int k0 = 0; k0 < 256; k0 += 32){
    for (int q2 = 0; q2 < 4; q2++){ int idx = tid + q2*256; int r = idx>>5, kk = idx&31;
      Ws_[r][kk] = w[(size_t)(e0+r)*256 + k0+kk]; }
    for (int q2 = 0; q2 < 8; q2++){ int idx = tid + q2*256; int r = idx>>6, ww = idx&63;
      Ss_[r][ww] = fmaxf(skip[(size_t)b*131072 + (size_t)(k0+r)*512 + n0+ww], 0.f); }
    __syncthreads();
    #pragma unroll
    for (int kk = 0; kk < 32; kk++){
      float t0 = Ws_[ty][kk], t1 = Ws_[ty+16][kk];
      float4 b4 = *(float4*)&Ss_[kk][tx*4];
      acc[0][0]+=t0*b4.x; acc[0][1]+=t0*b4.y; acc[0][2]+=t0*b4.z; acc[0][3]+=t0*b4.w;
      acc[1][0]+=t1*b4.x; acc[1][1]+=t1*b4.y; acc[1][2]+=t1*b4.z; acc[1][3]+=t1*b4.w;
    }
    __syncthreads();
  }
  for (int i2 = 0; i2 < 2; i2++){
    int e = e0 + ty + 16*i2;
    float bb = bias[e];
    float4 o4 = make_float4(fmaxf(acc[i2][0]+bb,0.f), fmaxf(acc[i2][1]+bb,0.f),
                            fmaxf(acc[i2][2]+bb,0.f), fmaxf(acc[i2][3]+bb,0.f));
    *(float4*)&h[(size_t)b*262144 + (size_t)e*512 + n0 + tx*4] = o4;
  }
}

__global__ void k_end2(const float* __restrict__ h, const float* __restrict__ w,
                       const float* __restrict__ bias, float* __restrict__ out){
  int n = blockIdx.x*256+threadIdx.x; int o=blockIdx.y; int b=blockIdx.z;
  float acc=bias[o];
  const float* hb=h + (size_t)b*262144 + n;
  #pragma unroll 8
  for (int e=0;e<512;e++) acc += w[o*512+e]*hb[(size_t)e*512];
  out[((size_t)b*12+o)*512+n]=acc;
}

extern "C" void kernel_launch(void* const* d_in, const int* in_sizes, int n_in,
                              void* d_out, int out_size, void* d_ws, size_t ws_size,
                              hipStream_t stream) {
  (void)in_sizes; (void)n_in; (void)out_size;
  const float* hist   =(const float*)d_in[0];
  const float* start_w=(const float*)d_in[1];
  const float* start_b=(const float*)d_in[2];
  const float* filt_w =(const float*)d_in[3];
  const float* filt_b =(const float*)d_in[4];
  const float* gate_w =(const float*)d_in[5];
  const float* gate_b =(const float*)d_in[6];
  const float* skip_w =(const float*)d_in[7];
  const float* skip_b =(const float*)d_in[8];
  const float* gconv_w=(const float*)d_in[9];
  const float* gconv_b=(const float*)d_in[10];
  const float* end1_w =(const float*)d_in[11];
  const float* end1_b =(const float*)d_in[12];
  const float* end2_w =(const float*)d_in[13];
  const float* end2_b =(const float*)d_in[14];
  const float* Ex1    =(const float*)d_in[15];
  const float* node1  =(const float*)d_in[16];
  const float* Wd     =(const float*)d_in[17];
  const float* Wxabs  =(const float*)d_in[18];
  const float* TiD    =(const float*)d_in[19];
  const float* DiW    =(const float*)d_in[20];
  const float* nv1    =(const float*)d_in[21];
  const float* nv2    =(const float*)d_in[22];

  char* ws = (char*)d_ws;
  const size_t needed = 83902464;
  if (ws_size < needed) return;

  // ---- persistent layout (bytes) ----
  ushort_t* PtA_hi  = (ushort_t*)(ws + 0);         //   524,288  A^T [m][512]
  ushort_t* PtA_lo  = (ushort_t*)(ws + 524288);
  ushort_t* PtA2_hi = (ushort_t*)(ws + 1048576);   //   524,288  (A^2)^T
  ushort_t* PtA2_lo = (ushort_t*)(ws + 1572864);
  ushort_t* PtB_hi  = (ushort_t*)(ws + 2097152);   // 8,388,608  B^T [b][m][512]
  ushort_t* PtB_lo  = (ushort_t*)(ws + 10485760);
  ushort_t* PtB2_hi = (ushort_t*)(ws + 18874368);  // 8,388,608  (B^2)^T
  ushort_t* PtB2_lo = (ushort_t*)(ws + 27262976);
  float*    stats   = (float*)(ws + 35651584);     // 128
  float*    part    = (float*)(ws + 35651712);     // 2,048 (pad to 16K)
  float*    skip    = (float*)(ws + 35667968);     // 8,388,608
  float*    fgL     = (float*)(ws + 44056576);     // 1,048,576
  ushort_t* fgh     = (ushort_t*)(ws + 45105152);  // 6,291,456  [b][t][c][512]
  ushort_t* fgl     = (ushort_t*)(ws + 51396608);  // 6,291,456
  float*    xA      = (float*)(ws + 57688064);     // 13,631,488 [b][t][c][512] (layer>=1)
  float*    xB      = (float*)(ws + 71319552);     // 12,582,912 lo<=12
  // ---- prologue aliases (region [44,056,576 .. 83,902,464) dead during prologue) ----
  float*    gwb     = (float*)(ws + 44056576);     // 1,048,576
  ushort_t* gws_hi  = (ushort_t*)(ws + 45105152);  //   524,288 (A non-T split)
  ushort_t* gws_lo  = (ushort_t*)(ws + 45629440);
  float*    ebuf    = (float*)(ws + 46153728);     // 4,980,736 (dead after k_adp)
  ushort_t* adjh    = (ushort_t*)(ws + 46153728);  // 4,194,304 (over ex-ebuf)
  float*    adp     = (float*)(ws + 51134464);     // 4,194,304
  float*    xw      = (float*)(ws + 55328768);     // 4,194,304
  float*    adjb    = (float*)(ws + 59523072);     // 16,777,216
  ushort_t* adjl    = (ushort_t*)(ws + 76300288);  // 4,194,304
  // ---- epilogue alias (fg/x dead after layer loop) ----
  float*    hbuf    = (float*)(ws + 45105152);     // 16,777,216

  // ======== prologue: adjacency supports ========
  k_embed<<<dim3(8192),dim3(64),0,stream>>>(hist,Ex1,node1,TiD,DiW,ebuf);
  k_adp<<<dim3(512),dim3(128),0,stream>>>(ebuf,Wd,adp);          // ebuf dead after this
  k_gw<<<dim3(512),dim3(256),0,stream>>>(nv1,nv2,gwb,gws_hi,gws_lo);
  k_splitT<<<dim3(16,16,1),dim3(256),0,stream>>>(gwb, 0, PtA_hi, 0, 512, PtA_lo, 0, 512);
  // A^2 power: (A^T)^2 -> PtA2 (split-write)
  k_pow<<<dim3(8,8,1),dim3(256),0,stream>>>(
      PtA_hi, PtA_lo, 0, gws_hi, gws_lo, 0, PtA2_hi, PtA2_lo, 0);
  k_lnp1<<<dim3(256),dim3(256),0,stream>>>(adp,part);
  k_lnp2<<<dim3(1),dim3(256),0,stream>>>(part,stats);
  k_xw<<<dim3(8192),dim3(128),0,stream>>>(adp,Wxabs,stats,xw);
  k_adjmm<<<dim3(8,16,16),dim3(256),0,stream>>>(xw,adp,stats,adjb);
  k_topk<<<dim3(8192),dim3(64),0,stream>>>(adjb, adjh, adjl);
  k_splitT<<<dim3(16,16,16),dim3(256),0,stream>>>(adjb, 262144, PtB_hi, 262144, 512,
                                                  PtB_lo, 262144, 512);
  // B^2 power per batch: (B^T)^2 -> PtB2 (split-write)
  k_pow<<<dim3(8,8,16),dim3(256),0,stream>>>(
      PtB_hi, PtB_lo, 262144, adjh, adjl, 262144, PtB2_hi, PtB2_lo, 262144);

  // ======== layer loop (k_start folded into layer-0 mix1) ========
  const int lin[8]={13,12,10,9,7,6,4,3};
  const int dil[8]={1,2,1,2,1,2,1,2};
  float* xcur=xA; float* alt=xB;
  for (int i=0;i<8;i++){
    int d=dil[i], li=lin[i], lo=li-d;
    const float* fwp=filt_w+(size_t)i*2048; const float* fbp=filt_b+i*32;
    const float* gwp=gate_w+(size_t)i*2048; const float* gbp=gate_b+i*32;
    const float* swp=skip_w+(size_t)i*8192; const float* sbp=skip_b+i*256;
    const float* gcwp=gconv_w+(size_t)i*5120; const float* gcbp=gconv_b+i*32;
    int M = 32*lo, Mt = (M+63)/64;

    k_mix1<<<dim3(2,lo,16),dim3(256),0,stream>>>(xcur, hist, start_w, start_b,
        (i==0)?1:0,
        fwp,fbp,gwp,gbp,gcwp,gcbp,
        fgh,fgl,fgL,alt,d,li,lo);
    k_skipacc<<<dim3(8,4,16),dim3(256),0,stream>>>(fgL,swp,sbp,skip,(i==0)?1:0);

    if (i < 7){
      k_gemms<<<dim3(Mt*8*16),dim3(256),0,stream>>>(
          fgh, fgl,
          PtA_hi, PtA_lo, PtA2_hi, PtA2_lo, PtB_hi, PtB_lo, PtB2_hi, PtB2_lo,
          gcwp, alt, Mt, M, lo);
    }
    float* tmp=xcur; xcur=alt; alt=tmp;
  }

  // ======== head ========
  k_end1t<<<dim3(8,16,16),dim3(256),0,stream>>>(skip,end1_w,end1_b,hbuf);
  k_end2<<<dim3(2,12,16),dim3(256),0,stream>>>(hbuf,end2_w,end2_b,(float*)d_out);
}